// Round 6
// baseline (923.849 us; speedup 1.0000x reference)
//
#include <hip/hip_runtime.h>
#include <math.h>

#define HEAD_DIM 128
#define NH 16
#define NKV 4
#define BB 4
#define TT 2048
#define DD 2048
#define ROWS (BB*TT)   // 8192

typedef unsigned short u16;
typedef unsigned int u32;
typedef __attribute__((ext_vector_type(8))) short short8;
typedef __attribute__((ext_vector_type(4))) float f32x4;
typedef __attribute__((ext_vector_type(16))) float f32x16;
typedef __attribute__((ext_vector_type(4))) unsigned short u16x4;

__device__ __forceinline__ float bf2f(u16 u) {
    union { unsigned int i; float f; } v; v.i = ((unsigned int)u) << 16; return v.f;
}
__device__ __forceinline__ u16 f2bf(float f) {
    union { float f; unsigned int i; } v; v.f = f;
    unsigned int r = v.i + 0x7FFFu + ((v.i >> 16) & 1u);   // round-to-nearest-even
    return (u16)(r >> 16);
}
__device__ __forceinline__ f32x4 mfma16(short8 a, short8 b, f32x4 c) {
    return __builtin_amdgcn_mfma_f32_16x16x32_bf16(a, b, c, 0, 0, 0);
}
__device__ __forceinline__ f32x16 mfma32(short8 a, short8 b, f32x16 c) {
    return __builtin_amdgcn_mfma_f32_32x32x16_bf16(a, b, c, 0, 0, 0);
}
__device__ __forceinline__ f32x16 zero16() {
    f32x16 z;
    #pragma unroll
    for (int i = 0; i < 16; ++i) z[i] = 0.f;
    return z;
}
// async global->LDS, 16B per lane; lds dest must be wave-uniform (HW adds lane*16)
__device__ __forceinline__ void gload_lds16(const u16* g, u16* l) {
    __builtin_amdgcn_global_load_lds(
        (const __attribute__((address_space(1))) unsigned int*)(const void*)g,
        (__attribute__((address_space(3))) unsigned int*)(void*)l, 16, 0, 0);
}

// ---------------------------------------------------------------------------
// fp32 -> bf16 cast
// ---------------------------------------------------------------------------
__global__ __launch_bounds__(256)
void cast_f2b(const float* __restrict__ in, u16* __restrict__ out, int n)
{
    int i = (blockIdx.x * 256 + threadIdx.x) * 4;
    if (i >= n) return;
    float4 v = *(const float4*)(in + i);
    u16x4 o;
    o.x = f2bf(v.x); o.y = f2bf(v.y); o.z = f2bf(v.z); o.w = f2bf(v.w);
    *(u16x4*)(out + i) = o;
}

// ---------------------------------------------------------------------------
// RoPE tables
// ---------------------------------------------------------------------------
__global__ __launch_bounds__(256)
void rope_table(float* __restrict__ cs, float* __restrict__ sn, float base)
{
    int idx = blockIdx.x * 256 + threadIdx.x;
    if (idx >= TT * 64) return;
    int t = idx >> 6;
    int d = idx & 63;
    float inv = powf(base, -(float)(2 * d) / 128.0f);
    float f = (float)t * inv;
    cs[idx] = cosf(f);
    sn[idx] = sinf(f);
}

// ---------------------------------------------------------------------------
// Fused per-head RMSNorm + rotary (+gain) with pre-scale folding.
// One 64-lane wave per row of 128; lane holds pair (d, d+64).
// relayout=0: out row = in row (in-place ok).
// relayout=1: out row = (b*heads + h)*T + t   (head-major for attention K).
// ---------------------------------------------------------------------------
__global__ __launch_bounds__(256)
void rmsrope_bf16(const u16* __restrict__ xin, u16* __restrict__ xout,
                  const float* __restrict__ cs, const float* __restrict__ sn,
                  const float* __restrict__ gain,
                  int heads, int use_gain, float pre, int relayout)
{
    int row  = blockIdx.x * 4 + (threadIdx.x >> 6);
    int lane = threadIdx.x & 63;
    int h = row % heads;
    int t = (row / heads) % TT;
    int b = row / (heads * TT);
    size_t base = (size_t)row * HEAD_DIM;

    float x1 = bf2f(xin[base + lane]);
    float x2 = bf2f(xin[base + 64 + lane]);
    float ss = x1 * x1 + x2 * x2;
    #pragma unroll
    for (int m = 1; m < 64; m <<= 1) ss += __shfl_xor(ss, m, 64);
    float r = 1.0f / sqrtf(ss * (1.0f / 128.0f) + 1.1920929e-7f);
    x1 *= r; x2 *= r;

    float c = cs[t * 64 + lane];
    float s = sn[t * 64 + lane];
    float o1 =  x1 * c + x2 * s;
    float o2 = -x1 * s + x2 * c;
    float g = use_gain ? gain[h] * pre : pre;
    o1 *= g; o2 *= g;

    size_t orow = relayout ? ((size_t)(b * heads + h) * TT + t) : (size_t)row;
    size_t obase = orow * HEAD_DIM;
    xout[obase + lane]      = f2bf(o1);
    xout[obase + 64 + lane] = f2bf(o2);
}

// ---------------------------------------------------------------------------
// V transpose+relayout: vbh [B,T,KVH,128] -> vt [B,KVH, T/64, 128, 64] (bf16)
// kt-tiled so attention fragment rows have 128B stride (L1-friendly).
// Within each 32-key block, position p holds key esw(p) (bits 2<->3 of the
// low-16 part) — the self-inverse permutation that makes PV B-fragments
// constructible fully in-lane (proven in round 5).
// ---------------------------------------------------------------------------
__global__ __launch_bounds__(256)
void transpose_v(const u16* __restrict__ vbh, u16* __restrict__ vtb)
{
    __shared__ u16 tile[64][72];
    const int tb = blockIdx.x;        // t block (64)
    const int db = blockIdx.y;        // d block (64)
    const int z  = blockIdx.z;        // b*NKV + kvh
    const int tid = threadIdx.x;

    {
        const int r = tid >> 2, cq = tid & 3;
        const u16* src = vbh + ((size_t)(((z >> 2) * TT + tb * 64 + r) * NKV + (z & 3))) * 128
                             + db * 64 + cq * 16;
        short8 s0 = *(const short8*)(src);
        short8 s1 = *(const short8*)(src + 8);
        #pragma unroll
        for (int e = 0; e < 8; ++e) tile[r][cq * 16 + e]     = (u16)s0[e];
        #pragma unroll
        for (int e = 0; e < 8; ++e) tile[r][cq * 16 + 8 + e] = (u16)s1[e];
    }
    __syncthreads();
    {
        const int d = tid >> 2, tq = tid & 3;
        __attribute__((aligned(16))) u16 tmp[16];
        #pragma unroll
        for (int e = 0; e < 16; ++e) {
            int esw = (e & 3) | ((e & 4) << 1) | ((e & 8) >> 1);  // swap bits 2,3
            tmp[e] = tile[tq * 16 + esw][d];
        }
        // vt[z][tb][d_global][key_pos]  with key_pos = tq*16 + e
        u16* dst = vtb + (((size_t)(z * (TT / 64) + tb) * 128 + (db * 64 + d)) << 6) + tq * 16;
        *(short8*)(dst)     = ((short8*)tmp)[0];
        *(short8*)(dst + 8) = ((short8*)tmp)[1];
    }
}

// ---------------------------------------------------------------------------
// bf16 MFMA GEMM (m97 structure): C[M,N] = A[M,K] @ W[N,K]^T
// 128x128 tile, BK=32, 4 waves (2x2 of 64x64), 16x16x32 MFMA.
// Staging via global_load_lds width-16 into LINEAR LDS [128][32].
// ---------------------------------------------------------------------------
template<int OUT_BF16>
__global__ __launch_bounds__(256)
void gemm_bf16_nt(const u16* __restrict__ A, const u16* __restrict__ W,
                  void* __restrict__ Cout, int M, int N, int K)
{
    __shared__ u16 As[128 * 32];
    __shared__ u16 Bs[128 * 32];
    const int tid = threadIdx.x;
    const int l = tid & 63, w = tid >> 6;
    const int lq = l & 15, lg = l >> 4;
    const int bm = blockIdx.y << 7, bn = blockIdx.x << 7;
    const int wr = (w >> 1) << 6, wc = (w & 1) << 6;

    f32x4 acc[4][4];
    #pragma unroll
    for (int m = 0; m < 4; ++m)
        #pragma unroll
        for (int n = 0; n < 4; ++n)
            acc[m][n] = (f32x4){0.f, 0.f, 0.f, 0.f};

    // staging: round r (0,1), wave w covers rows r*64 + w*16 + lane/4,
    // 16B at col (lane&3)*8 elems; LDS dest = (r*64 + w*16)*32 (wave-uniform)
    const int srowA = w * 16 + (l >> 2);
    const int scol  = (l & 3) << 3;
    const u16* ag0 = A + (size_t)(bm + srowA) * K + scol;
    const u16* ag1 = A + (size_t)(bm + 64 + srowA) * K + scol;
    const u16* bg0 = W + (size_t)(bn + srowA) * K + scol;
    const u16* bg1 = W + (size_t)(bn + 64 + srowA) * K + scol;
    u16* asd0 = As + (w * 16) * 32;
    u16* asd1 = As + (64 + w * 16) * 32;
    u16* bsd0 = Bs + (w * 16) * 32;
    u16* bsd1 = Bs + (64 + w * 16) * 32;

    for (int kt = 0; kt < K; kt += 32) {
        __syncthreads();                 // prior iter LDS reads done
        gload_lds16(ag0 + kt, asd0);
        gload_lds16(ag1 + kt, asd1);
        gload_lds16(bg0 + kt, bsd0);
        gload_lds16(bg1 + kt, bsd1);
        __syncthreads();                 // vmcnt(0) drain -> LDS ready

        short8 af[4], bf[4];
        #pragma unroll
        for (int m = 0; m < 4; ++m)
            af[m] = *(const short8*)(As + (wr + m * 16 + lq) * 32 + lg * 8);
        #pragma unroll
        for (int n = 0; n < 4; ++n)
            bf[n] = *(const short8*)(Bs + (wc + n * 16 + lq) * 32 + lg * 8);
        #pragma unroll
        for (int m = 0; m < 4; ++m)
            #pragma unroll
            for (int n = 0; n < 4; ++n)
                acc[m][n] = mfma16(af[m], bf[n], acc[m][n]);
    }

    // C/D layout: col = lane&15, row = (lane>>4)*4 + reg
    #pragma unroll
    for (int m = 0; m < 4; ++m) {
        int grow = bm + wr + m * 16 + lg * 4;
        #pragma unroll
        for (int n = 0; n < 4; ++n) {
            int gcol = bn + wc + n * 16 + lq;
            #pragma unroll
            for (int q = 0; q < 4; ++q) {
                if (OUT_BF16)
                    ((u16*)Cout)[(size_t)(grow + q) * N + gcol] = f2bf(acc[m][n][q]);
                else
                    ((float*)Cout)[(size_t)(grow + q) * N + gcol] = acc[m][n][q];
            }
        }
    }
}

// ---------------------------------------------------------------------------
// Causal attention, swapped-operand 32x32x16 MFMA, no LDS, no barriers.
// Each 64-lane wave owns 32 q-rows (query = lane&31). Per 64-key tile:
//   S^T = mfma(A=K, B=Q); softmax fully in-register (+1 shfl_xor(32));
//   P -> bf16 B-frags in-lane (V^T key-permutation absorbs layout);
//   O^T = mfma(A=V^T, B=P^T).
// K in [B,KVH,T,128] (256B rows), V^T in [B,KVH,T/64,128,64] (128B rows):
// fragment loads sweep a 16KB/tile window with full cache-line reuse.
// Scores arrive in exp2 domain (scale*log2e folded into Q by rmsrope).
// ---------------------------------------------------------------------------
__global__ __launch_bounds__(256, 4)
void attn_mfma(const u16* __restrict__ qg, const u16* __restrict__ kg,
               const u16* __restrict__ vtg, u16* __restrict__ yg)
{
    const int h = blockIdx.y, b = blockIdx.z, kvh = h >> 2;
    const int tid = threadIdx.x;
    const int wid = tid >> 6, l = tid & 63;
    const int lq = l & 31, hi = l >> 5;
    const int hi4 = hi << 2;
    const int qsl = 63 - ((int)blockIdx.x * 4 + wid);   // heavy slots first
    const int qb = qsl * 32;
    const int qrow = qb + lq;                           // this lane's query token

    // Q fragments (B-operand): 8 k-slices of 16; lane = (query, hi-half of k)
    const u16* qptr = qg + ((size_t)((b * TT + qrow) * NH + h) << 7) + hi * 8;
    short8 qf[8];
    #pragma unroll
    for (int s = 0; s < 8; ++s)
        qf[s] = *(const short8*)(qptr + s * 16);

    f32x16 accO[4];
    #pragma unroll
    for (int db = 0; db < 4; ++db) accO[db] = zero16();
    float m2 = -1e30f, lr = 0.f;

    // K: lane covers key row (kb*32 + lq) at d-offset hi*8; 256B rows
    const u16* kptr = kg + (((size_t)(b * NKV + kvh) * TT + lq) << 7) + hi * 8;
    // V^T: lane covers d-row (db*32 + lq) at key-pos hi*8; 128B rows, kt-tiled
    const u16* vptr = vtg + (((size_t)(b * NKV + kvh) * (TT / 64) * 128 + lq) << 6) + hi * 8;

    const int ktmax = (qb + 31) >> 6;
    for (int kt = 0; kt <= ktmax; ++kt) {
        // ---- S^T = K·Q (2 key-blocks x 8 slices = 16 MFMA) ----
        const u16* kbase = kptr + (size_t)kt * 8192;      // 64 keys * 128
        f32x16 accS0 = zero16(), accS1 = zero16();
        __builtin_amdgcn_s_setprio(1);
        #pragma unroll
        for (int s = 0; s < 8; ++s) {
            short8 kf0 = *(const short8*)(kbase + s * 16);
            accS0 = mfma32(kf0, qf[s], accS0);
        }
        #pragma unroll
        for (int s = 0; s < 8; ++s) {
            short8 kf1 = *(const short8*)(kbase + 32 * 128 + s * 16);
            accS1 = mfma32(kf1, qf[s], accS1);
        }
        __builtin_amdgcn_s_setprio(0);

        // ---- gather scores (mask on diag tile only) ----
        // p[kb*16 + r] = P[query=lq][key = kt*64 + kb*32 + (r&3)+8*(r>>2)+4*hi]
        float p[32];
        if (kt == ktmax) {
            #pragma unroll
            for (int r = 0; r < 16; ++r) {
                int key0 = kt * 64 + (r & 3) + 8 * (r >> 2) + hi4;
                p[r]      = (key0      > qrow) ? -INFINITY : accS0[r];
                p[16 + r] = (key0 + 32 > qrow) ? -INFINITY : accS1[r];
            }
        } else {
            #pragma unroll
            for (int r = 0; r < 16; ++r) { p[r] = accS0[r]; p[16 + r] = accS1[r]; }
        }

        // ---- row max (in-register tree + cross-half combine) ----
        float t16[16];
        #pragma unroll
        for (int i = 0; i < 16; ++i) t16[i] = fmaxf(p[i], p[i + 16]);
        #pragma unroll
        for (int i = 0; i < 8; ++i) t16[i] = fmaxf(t16[i], t16[i + 8]);
        #pragma unroll
        for (int i = 0; i < 4; ++i) t16[i] = fmaxf(t16[i], t16[i + 4]);
        float pm = fmaxf(fmaxf(t16[0], t16[1]), fmaxf(t16[2], t16[3]));
        pm = fmaxf(pm, __shfl_xor(pm, 32, 64));

        // ---- defer-max: skip O-rescale when max barely grew ----
        float mn = m2;
        if (!__all(pm - m2 <= 8.0f)) {
            mn = fmaxf(m2, pm);
            float al = exp2f(m2 - mn);
            lr *= al;
            #pragma unroll
            for (int db = 0; db < 4; ++db) accO[db] *= al;
            m2 = mn;
        }

        // ---- exp2 + row sum ----
        #pragma unroll
        for (int r = 0; r < 32; ++r) p[r] = exp2f(p[r] - mn);
        #pragma unroll
        for (int i = 0; i < 16; ++i) t16[i] = p[i] + p[i + 16];
        #pragma unroll
        for (int i = 0; i < 8; ++i) t16[i] += t16[i + 8];
        #pragma unroll
        for (int i = 0; i < 4; ++i) t16[i] += t16[i + 4];
        float rs = (t16[0] + t16[1]) + (t16[2] + t16[3]);
        rs += __shfl_xor(rs, 32, 64);
        lr += rs;

        // ---- P -> bf16 B-fragments, fully in-lane (V^T key-permutation) ----
        short8 pfrag[4];
        #pragma unroll
        for (int kb = 0; kb < 2; ++kb)
            #pragma unroll
            for (int c = 0; c < 2; ++c) {
                union { u16 e[8]; short8 s; } f;
                #pragma unroll
                for (int j = 0; j < 8; ++j)
                    f.e[j] = f2bf(p[kb * 16 + 8 * c + j]);
                pfrag[kb * 2 + c] = f.s;
            }

        // ---- O^T += V^T · P^T (4 d-blocks x 4 key-slices = 16 MFMA) ----
        const u16* vbase = vptr + (size_t)kt * 8192;      // 128 d * 64 keys
        #pragma unroll
        for (int db = 0; db < 4; ++db) {
            short8 vf0 = *(const short8*)(vbase + db * 32 * 64);
            short8 vf1 = *(const short8*)(vbase + db * 32 * 64 + 16);
            short8 vf2 = *(const short8*)(vbase + db * 32 * 64 + 32);
            short8 vf3 = *(const short8*)(vbase + db * 32 * 64 + 48);
            __builtin_amdgcn_s_setprio(1);
            accO[db] = mfma32(vf0, pfrag[0], accO[db]);
            accO[db] = mfma32(vf1, pfrag[1], accO[db]);
            accO[db] = mfma32(vf2, pfrag[2], accO[db]);
            accO[db] = mfma32(vf3, pfrag[3], accO[db]);
            __builtin_amdgcn_s_setprio(0);
        }
    }

    // ---- epilogue: normalize (lr lane-uniform) and store ----
    float inv = 1.0f / lr;
    u16* yrow = yg + ((size_t)((b * TT + qrow) * NH + h) << 7);
    #pragma unroll
    for (int db = 0; db < 4; ++db)
        #pragma unroll
        for (int r = 0; r < 4; ++r) {
            u16x4 o;
            #pragma unroll
            for (int q = 0; q < 4; ++q) o[q] = f2bf(accO[db][4 * r + q] * inv);
            *(u16x4*)(yrow + db * 32 + 8 * r + hi4) = o;
        }
}

// ---------------------------------------------------------------------------
extern "C" void kernel_launch(void* const* d_in, const int* in_sizes, int n_in,
                              void* d_out, int out_size, void* d_ws, size_t ws_size,
                              hipStream_t stream)
{
    const float* x      = (const float*)d_in[0];
    const float* q_w    = (const float*)d_in[1];
    const float* k_w    = (const float*)d_in[2];
    const float* v_w    = (const float*)d_in[3];
    const float* out_w  = (const float*)d_in[4];
    const float* q_gain = (const float*)d_in[5];
    float* out = (float*)d_out;

    char* ws = (char*)d_ws;
    u16* qh   = (u16*)(ws);                       // 33,554,432 B  [B,T,NH,128]
    u16* kh   = (u16*)(ws + 33554432ull);         //  8,388,608   [B,T,KVH,128]
    u16* vbh  = (u16*)(ws + 41943040ull);         //  8,388,608   [B,T,KVH,128]
    u16* vtb  = (u16*)(ws + 50331648ull);         //  8,388,608   [B,KVH,T/64,128,64]
    u16* xh   = (u16*)(ws + 58720256ull);         // 33,554,432   (xh, later y)
    u16* wbuf = (u16*)(ws + 92274688ull);         //  8,388,608   (weights; then kk)
    float* cs = (float*)(ws + 100663296ull);      //    524,288
    float* sn = cs + TT * 64;                     //    524,288   (total 101,711,872)
    u16* kk   = wbuf;                             // [B,KVH,T,128] aliases wbuf

    dim3 blk(256);

    // rope tables (T=2048 > train 1024 -> NTK base scaling)
    double base = 10000.0 * pow((double)TT / 1024.0, 128.0 / 126.0);
    rope_table<<<(TT * 64) / 256, blk, 0, stream>>>(cs, sn, (float)base);

    // cast activations
    cast_f2b<<<(ROWS * DD) / 1024, blk, 0, stream>>>(x, xh, ROWS * DD);

    // projections (weight cast -> gemm, shared weight buffer)
    cast_f2b<<<(DD * DD) / 1024, blk, 0, stream>>>(q_w, wbuf, DD * DD);
    gemm_bf16_nt<1><<<dim3(DD / 128, ROWS / 128), blk, 0, stream>>>(xh, wbuf, qh, ROWS, DD, DD);
    cast_f2b<<<(512 * DD) / 1024, blk, 0, stream>>>(k_w, wbuf, 512 * DD);
    gemm_bf16_nt<1><<<dim3(512 / 128, ROWS / 128), blk, 0, stream>>>(xh, wbuf, kh, ROWS, 512, DD);
    cast_f2b<<<(512 * DD) / 1024, blk, 0, stream>>>(v_w, wbuf, 512 * DD);
    gemm_bf16_nt<1><<<dim3(512 / 128, ROWS / 128), blk, 0, stream>>>(xh, wbuf, vbh, ROWS, 512, DD);

    // fused rmsnorm + rope; Q in-place (+gain*scale*log2e); K relayouted to
    // head-major [B,KVH,T,128] into kk (aliases wbuf — weights dead now)
    const float pre_q = 0.08838834764831845f * 1.4426950408889634f;
    rmsrope_bf16<<<(ROWS * NH) / 4, blk, 0, stream>>>(qh, qh, cs, sn, q_gain, NH, 1, pre_q, 0);
    rmsrope_bf16<<<(ROWS * NKV) / 4, blk, 0, stream>>>(kh, kk, cs, sn, nullptr, NKV, 0, 1.0f, 1);

    // V -> [B,KVH,T/64,128,64] with per-32 key permutation
    transpose_v<<<dim3(TT / 64, 2, BB * NKV), blk, 0, stream>>>(vbh, vtb);

    // attention -> y (reuses xh region; xh dead after projections)
    attn_mfma<<<dim3(16, NH, BB), blk, 0, stream>>>(qh, kk, vtb, xh);

    // output projection (fp32 out); wbuf overwrite is safe (kk dead after attn)
    cast_f2b<<<(DD * DD) / 1024, blk, 0, stream>>>(out_w, wbuf, DD * DD);
    gemm_bf16_nt<0><<<dim3(DD / 128, ROWS / 128), blk, 0, stream>>>(xh, wbuf, out, ROWS, DD, DD);
}

// Round 7
// 549.339 us; speedup vs baseline: 1.6817x; 1.6817x over previous
//
#include <hip/hip_runtime.h>
#include <math.h>

#define HEAD_DIM 128
#define NH 16
#define NKV 4
#define BB 4
#define TT 2048
#define DD 2048
#define ROWS (BB*TT)   // 8192

typedef unsigned short u16;
typedef unsigned int u32;
typedef __attribute__((ext_vector_type(8))) short short8;
typedef __attribute__((ext_vector_type(4))) float f32x4;
typedef __attribute__((ext_vector_type(16))) float f32x16;
typedef __attribute__((ext_vector_type(4))) unsigned short u16x4;

__device__ __forceinline__ float bf2f(u16 u) {
    union { unsigned int i; float f; } v; v.i = ((unsigned int)u) << 16; return v.f;
}
__device__ __forceinline__ u16 f2bf(float f) {
    union { float f; unsigned int i; } v; v.f = f;
    unsigned int r = v.i + 0x7FFFu + ((v.i >> 16) & 1u);   // round-to-nearest-even
    return (u16)(r >> 16);
}
__device__ __forceinline__ f32x4 mfma16(short8 a, short8 b, f32x4 c) {
    return __builtin_amdgcn_mfma_f32_16x16x32_bf16(a, b, c, 0, 0, 0);
}
__device__ __forceinline__ f32x16 mfma32(short8 a, short8 b, f32x16 c) {
    return __builtin_amdgcn_mfma_f32_32x32x16_bf16(a, b, c, 0, 0, 0);
}
__device__ __forceinline__ f32x16 zero16() {
    f32x16 z;
    #pragma unroll
    for (int i = 0; i < 16; ++i) z[i] = 0.f;
    return z;
}
// async global->LDS, 16B per lane; lds dest wave-uniform (HW adds lane*16)
__device__ __forceinline__ void gload_lds16(const u16* g, u16* l) {
    __builtin_amdgcn_global_load_lds(
        (const __attribute__((address_space(1))) unsigned int*)(const void*)g,
        (__attribute__((address_space(3))) unsigned int*)(void*)l, 16, 0, 0);
}

// ---------------------------------------------------------------------------
// fp32 -> bf16 cast
// ---------------------------------------------------------------------------
__global__ __launch_bounds__(256)
void cast_f2b(const float* __restrict__ in, u16* __restrict__ out, int n)
{
    int i = (blockIdx.x * 256 + threadIdx.x) * 4;
    if (i >= n) return;
    float4 v = *(const float4*)(in + i);
    u16x4 o;
    o.x = f2bf(v.x); o.y = f2bf(v.y); o.z = f2bf(v.z); o.w = f2bf(v.w);
    *(u16x4*)(out + i) = o;
}

// ---------------------------------------------------------------------------
// RoPE tables
// ---------------------------------------------------------------------------
__global__ __launch_bounds__(256)
void rope_table(float* __restrict__ cs, float* __restrict__ sn, float base)
{
    int idx = blockIdx.x * 256 + threadIdx.x;
    if (idx >= TT * 64) return;
    int t = idx >> 6;
    int d = idx & 63;
    float inv = powf(base, -(float)(2 * d) / 128.0f);
    float f = (float)t * inv;
    cs[idx] = cosf(f);
    sn[idx] = sinf(f);
}

// ---------------------------------------------------------------------------
// Fused per-head RMSNorm + rotary (+gain) with pre-scale folding.
// One 64-lane wave per row of 128; lane holds pair (d, d+64).
// relayout=0: out row = in row (in-place ok).
// relayout=1: out row = (b*heads + h)*T + t   (head-major).
// ---------------------------------------------------------------------------
__global__ __launch_bounds__(256)
void rmsrope_bf16(const u16* __restrict__ xin, u16* __restrict__ xout,
                  const float* __restrict__ cs, const float* __restrict__ sn,
                  const float* __restrict__ gain,
                  int heads, int use_gain, float pre, int relayout)
{
    int row  = blockIdx.x * 4 + (threadIdx.x >> 6);
    int lane = threadIdx.x & 63;
    int h = row % heads;
    int t = (row / heads) % TT;
    int b = row / (heads * TT);
    size_t base = (size_t)row * HEAD_DIM;

    float x1 = bf2f(xin[base + lane]);
    float x2 = bf2f(xin[base + 64 + lane]);
    float ss = x1 * x1 + x2 * x2;
    #pragma unroll
    for (int m = 1; m < 64; m <<= 1) ss += __shfl_xor(ss, m, 64);
    float r = 1.0f / sqrtf(ss * (1.0f / 128.0f) + 1.1920929e-7f);
    x1 *= r; x2 *= r;

    float c = cs[t * 64 + lane];
    float s = sn[t * 64 + lane];
    float o1 =  x1 * c + x2 * s;
    float o2 = -x1 * s + x2 * c;
    float g = use_gain ? gain[h] * pre : pre;
    o1 *= g; o2 *= g;

    size_t orow = relayout ? ((size_t)(b * heads + h) * TT + t) : (size_t)row;
    size_t obase = orow * HEAD_DIM;
    xout[obase + lane]      = f2bf(o1);
    xout[obase + 64 + lane] = f2bf(o2);
}

// ---------------------------------------------------------------------------
// V transpose+relayout: vbh [B,T,KVH,128] -> vt [B,KVH, T/64, 128, 64] (bf16)
// kt-tiled; per-32 key permutation (bits 2<->3) so PV B-fragments are
// in-lane (proven round 5/6).
// ---------------------------------------------------------------------------
__global__ __launch_bounds__(256)
void transpose_v(const u16* __restrict__ vbh, u16* __restrict__ vtb)
{
    __shared__ u16 tile[64][72];
    const int tb = blockIdx.x;        // t block (64)
    const int db = blockIdx.y;        // d block (64)
    const int z  = blockIdx.z;        // b*NKV + kvh
    const int tid = threadIdx.x;

    {
        const int r = tid >> 2, cq = tid & 3;
        const u16* src = vbh + ((size_t)(((z >> 2) * TT + tb * 64 + r) * NKV + (z & 3))) * 128
                             + db * 64 + cq * 16;
        short8 s0 = *(const short8*)(src);
        short8 s1 = *(const short8*)(src + 8);
        #pragma unroll
        for (int e = 0; e < 8; ++e) tile[r][cq * 16 + e]     = (u16)s0[e];
        #pragma unroll
        for (int e = 0; e < 8; ++e) tile[r][cq * 16 + 8 + e] = (u16)s1[e];
    }
    __syncthreads();
    {
        const int d = tid >> 2, tq = tid & 3;
        __attribute__((aligned(16))) u16 tmp[16];
        #pragma unroll
        for (int e = 0; e < 16; ++e) {
            int esw = (e & 3) | ((e & 4) << 1) | ((e & 8) >> 1);  // swap bits 2,3
            tmp[e] = tile[tq * 16 + esw][d];
        }
        u16* dst = vtb + (((size_t)(z * (TT / 64) + tb) * 128 + (db * 64 + d)) << 6) + tq * 16;
        *(short8*)(dst)     = ((short8*)tmp)[0];
        *(short8*)(dst + 8) = ((short8*)tmp)[1];
    }
}

// ---------------------------------------------------------------------------
// bf16 MFMA GEMM (m97 structure): C[M,N] = A[M,K] @ W[N,K]^T
// 128x128 tile, BK=32, 4 waves, global_load_lds staging, linear LDS.
// ---------------------------------------------------------------------------
template<int OUT_BF16>
__global__ __launch_bounds__(256)
void gemm_bf16_nt(const u16* __restrict__ A, const u16* __restrict__ W,
                  void* __restrict__ Cout, int M, int N, int K)
{
    __shared__ u16 As[128 * 32];
    __shared__ u16 Bs[128 * 32];
    const int tid = threadIdx.x;
    const int l = tid & 63, w = tid >> 6;
    const int lq = l & 15, lg = l >> 4;
    const int bm = blockIdx.y << 7, bn = blockIdx.x << 7;
    const int wr = (w >> 1) << 6, wc = (w & 1) << 6;

    f32x4 acc[4][4];
    #pragma unroll
    for (int m = 0; m < 4; ++m)
        #pragma unroll
        for (int n = 0; n < 4; ++n)
            acc[m][n] = (f32x4){0.f, 0.f, 0.f, 0.f};

    const int srowA = w * 16 + (l >> 2);
    const int scol  = (l & 3) << 3;
    const u16* ag0 = A + (size_t)(bm + srowA) * K + scol;
    const u16* ag1 = A + (size_t)(bm + 64 + srowA) * K + scol;
    const u16* bg0 = W + (size_t)(bn + srowA) * K + scol;
    const u16* bg1 = W + (size_t)(bn + 64 + srowA) * K + scol;
    u16* asd0 = As + (w * 16) * 32;
    u16* asd1 = As + (64 + w * 16) * 32;
    u16* bsd0 = Bs + (w * 16) * 32;
    u16* bsd1 = Bs + (64 + w * 16) * 32;

    for (int kt = 0; kt < K; kt += 32) {
        __syncthreads();
        gload_lds16(ag0 + kt, asd0);
        gload_lds16(ag1 + kt, asd1);
        gload_lds16(bg0 + kt, bsd0);
        gload_lds16(bg1 + kt, bsd1);
        __syncthreads();

        short8 af[4], bf[4];
        #pragma unroll
        for (int m = 0; m < 4; ++m)
            af[m] = *(const short8*)(As + (wr + m * 16 + lq) * 32 + lg * 8);
        #pragma unroll
        for (int n = 0; n < 4; ++n)
            bf[n] = *(const short8*)(Bs + (wc + n * 16 + lq) * 32 + lg * 8);
        #pragma unroll
        for (int m = 0; m < 4; ++m)
            #pragma unroll
            for (int n = 0; n < 4; ++n)
                acc[m][n] = mfma16(af[m], bf[n], acc[m][n]);
    }

    #pragma unroll
    for (int m = 0; m < 4; ++m) {
        int grow = bm + wr + m * 16 + lg * 4;
        #pragma unroll
        for (int n = 0; n < 4; ++n) {
            int gcol = bn + wc + n * 16 + lq;
            #pragma unroll
            for (int q = 0; q < 4; ++q) {
                if (OUT_BF16)
                    ((u16*)Cout)[(size_t)(grow + q) * N + gcol] = f2bf(acc[m][n][q]);
                else
                    ((float*)Cout)[(size_t)(grow + q) * N + gcol] = acc[m][n][q];
            }
        }
    }
}

// ---------------------------------------------------------------------------
// Causal attention: 4 waves cooperate on a 128-row Q block; K/V tiles LDS-
// staged (double-buffered, global_load_lds) and shared by all waves.
// Swapped-operand 32x32x16 MFMA core (round-5/6 proven): query = lane&31,
// softmax fully in-register, PV B-frags in-lane via V key-permutation.
// LDS reads XOR-swizzled (chunk ^= row&7) with inverse-swizzled global
// source (rule #21: linear dest + pre-swizzled src + swizzled read).
// 2-phase pipeline: issue next-tile STAGE before computing current tile;
// one vmcnt(0)+barrier per tile (in __syncthreads).
// ---------------------------------------------------------------------------
__global__ __launch_bounds__(256, 2)
void attn_mfma(const u16* __restrict__ qg,   // [B,NH,T,128] head-major, pre-scaled
               const u16* __restrict__ kg,   // [B,KVH,T,128]
               const u16* __restrict__ vtg,  // [B,KVH,T/64,128,64] key-permuted
               u16* __restrict__ yg)         // [B,T,NH,128]
{
    __shared__ u16 Ks[2][64 * 128];   // [key][d]  16KB each
    __shared__ u16 Vs[2][128 * 64];   // [d][key]  16KB each

    const int h = blockIdx.y, b = blockIdx.z, kvh = h >> 2;
    const int tid = threadIdx.x, wid = tid >> 6, l = tid & 63;
    const int lq = l & 31, hi = l >> 5, hi4 = hi << 2;
    const int qblk = 15 - (int)blockIdx.x;            // heavy blocks first
    const int qrow = qblk * 128 + wid * 32 + lq;      // this lane's query token
    const int diag = (qblk * 128 + wid * 32) >> 6;    // wave's diagonal tile
    const int nt = qblk * 2 + 2;                      // tiles for this block

    // ---- Q fragments (coalesced, head-major) ----
    const u16* qptr = qg + (((size_t)(b * NH + h) * TT + qrow) << 7) + hi * 8;
    short8 qf[8];
    #pragma unroll
    for (int s = 0; s < 8; ++s)
        qf[s] = *(const short8*)(qptr + s * 16);

    f32x16 accO[4];
    #pragma unroll
    for (int d = 0; d < 4; ++d) accO[d] = zero16();
    float m2 = -1e30f, lr = 0.f;

    // ---- staging decomposition (per wave: 4 issues K + 4 issues V) ----
    const int krow_off = l >> 4;                 // 0..3 (row within 1KB issue)
    const int kchunk   = l & 15;                 // 16B chunk within 256B row
    const int vrow_off = l >> 3;                 // 0..7
    const int vchunk_s = (l & 7) ^ (l >> 3);     // pre-swizzled V source chunk
    const u16* kg_bh = kg + (((size_t)(b * NKV + kvh) * TT) << 7);
    const u16* vt_bh = vtg + (size_t)(b * NKV + kvh) * (TT / 64) * 8192;

    auto stage = [&](int buf, int kt) {
        const u16* ksrc = kg_bh + (((size_t)(kt * 64 + wid * 16)) << 7);
        const u16* vsrc = vt_bh + (size_t)kt * 8192 + wid * 2048;
        u16* kd = &Ks[buf][wid * 2048];
        u16* vd = &Vs[buf][wid * 2048];
        #pragma unroll
        for (int i = 0; i < 4; ++i) {
            int kr = i * 4 + krow_off;
            gload_lds16(ksrc + ((size_t)kr << 7) + ((kchunk ^ (kr & 7)) << 3), kd + i * 512);
            int vr = i * 8 + vrow_off;
            gload_lds16(vsrc + ((size_t)vr << 6) + (vchunk_s << 3), vd + i * 512);
        }
    };

    stage(0, 0);
    __syncthreads();
    int cur = 0;

    for (int kt = 0; kt < nt; ++kt) {
        if (kt + 1 < nt) stage(cur ^ 1, kt + 1);

        if (kt <= diag) {
            // ---- S^T = K·Q (16 MFMA), K from LDS (swizzled reads) ----
            const u16* Kc = Ks[cur];
            f32x16 accS0 = zero16(), accS1 = zero16();
            __builtin_amdgcn_s_setprio(1);
            #pragma unroll
            for (int s = 0; s < 8; ++s) {
                int c = ((2 * s + hi) ^ (lq & 7)) << 3;
                short8 kf0 = *(const short8*)(Kc + ((size_t)lq << 7) + c);
                accS0 = mfma32(kf0, qf[s], accS0);
                short8 kf1 = *(const short8*)(Kc + ((size_t)(32 + lq) << 7) + c);
                accS1 = mfma32(kf1, qf[s], accS1);
            }
            __builtin_amdgcn_s_setprio(0);

            // ---- scores + causal mask (diag tile only) ----
            float p[32];
            if (kt == diag) {
                #pragma unroll
                for (int r = 0; r < 16; ++r) {
                    int key0 = kt * 64 + (r & 3) + 8 * (r >> 2) + hi4;
                    p[r]      = (key0      > qrow) ? -INFINITY : accS0[r];
                    p[16 + r] = (key0 + 32 > qrow) ? -INFINITY : accS1[r];
                }
            } else {
                #pragma unroll
                for (int r = 0; r < 16; ++r) { p[r] = accS0[r]; p[16 + r] = accS1[r]; }
            }

            // ---- row max (in-register tree + cross-half combine) ----
            float t16[16];
            #pragma unroll
            for (int i = 0; i < 16; ++i) t16[i] = fmaxf(p[i], p[i + 16]);
            #pragma unroll
            for (int i = 0; i < 8; ++i) t16[i] = fmaxf(t16[i], t16[i + 8]);
            #pragma unroll
            for (int i = 0; i < 4; ++i) t16[i] = fmaxf(t16[i], t16[i + 4]);
            float pm = fmaxf(fmaxf(t16[0], t16[1]), fmaxf(t16[2], t16[3]));
            pm = fmaxf(pm, __shfl_xor(pm, 32, 64));

            // ---- defer-max ----
            float mn = m2;
            if (!__all(pm - m2 <= 8.0f)) {
                mn = fmaxf(m2, pm);
                float al = exp2f(m2 - mn);
                lr *= al;
                #pragma unroll
                for (int d = 0; d < 4; ++d) accO[d] *= al;
                m2 = mn;
            }

            // ---- exp2 + row sum ----
            #pragma unroll
            for (int r = 0; r < 32; ++r) p[r] = exp2f(p[r] - mn);
            #pragma unroll
            for (int i = 0; i < 16; ++i) t16[i] = p[i] + p[i + 16];
            #pragma unroll
            for (int i = 0; i < 8; ++i) t16[i] += t16[i + 8];
            #pragma unroll
            for (int i = 0; i < 4; ++i) t16[i] += t16[i + 4];
            float rs = (t16[0] + t16[1]) + (t16[2] + t16[3]);
            rs += __shfl_xor(rs, 32, 64);
            lr += rs;

            // ---- P -> bf16 B-fragments, in-lane ----
            short8 pfrag[4];
            #pragma unroll
            for (int kb = 0; kb < 2; ++kb)
                #pragma unroll
                for (int c = 0; c < 2; ++c) {
                    union { u16 e[8]; short8 s; } f;
                    #pragma unroll
                    for (int j = 0; j < 8; ++j)
                        f.e[j] = f2bf(p[kb * 16 + 8 * c + j]);
                    pfrag[kb * 2 + c] = f.s;
                }

            // ---- O^T += V^T · P^T (16 MFMA), V from LDS (swizzled reads) ----
            const u16* Vc = Vs[cur];
            #pragma unroll
            for (int d = 0; d < 4; ++d) {
                const u16* vrow = Vc + ((size_t)(d * 32 + lq) << 6);
                short8 vf0 = *(const short8*)(vrow + (((0 + hi) ^ (lq & 7)) << 3));
                short8 vf1 = *(const short8*)(vrow + (((2 + hi) ^ (lq & 7)) << 3));
                short8 vf2 = *(const short8*)(vrow + (((4 + hi) ^ (lq & 7)) << 3));
                short8 vf3 = *(const short8*)(vrow + (((6 + hi) ^ (lq & 7)) << 3));
                __builtin_amdgcn_s_setprio(1);
                accO[d] = mfma32(vf0, pfrag[0], accO[d]);
                accO[d] = mfma32(vf1, pfrag[1], accO[d]);
                accO[d] = mfma32(vf2, pfrag[2], accO[d]);
                accO[d] = mfma32(vf3, pfrag[3], accO[d]);
                __builtin_amdgcn_s_setprio(0);
            }
        }

        __syncthreads();
        cur ^= 1;
    }

    // ---- epilogue: normalize (lr lane-uniform) and store ----
    float inv = 1.0f / lr;
    u16* yrow = yg + ((size_t)((b * TT + qrow) * NH + h) << 7);
    #pragma unroll
    for (int d = 0; d < 4; ++d)
        #pragma unroll
        for (int r = 0; r < 4; ++r) {
            u16x4 o;
            #pragma unroll
            for (int q = 0; q < 4; ++q) o[q] = f2bf(accO[d][4 * r + q] * inv);
            *(u16x4*)(yrow + d * 32 + 8 * r + hi4) = o;
        }
}

// ---------------------------------------------------------------------------
extern "C" void kernel_launch(void* const* d_in, const int* in_sizes, int n_in,
                              void* d_out, int out_size, void* d_ws, size_t ws_size,
                              hipStream_t stream)
{
    const float* x      = (const float*)d_in[0];
    const float* q_w    = (const float*)d_in[1];
    const float* k_w    = (const float*)d_in[2];
    const float* v_w    = (const float*)d_in[3];
    const float* out_w  = (const float*)d_in[4];
    const float* q_gain = (const float*)d_in[5];
    float* out = (float*)d_out;

    char* ws = (char*)d_ws;
    u16* qh   = (u16*)(ws);                       // 32MB [B,T,NH,128] proj-Q; later y
    u16* kh   = (u16*)(ws + 33554432ull);         //  8MB [B,T,KVH,128]
    u16* vbh  = (u16*)(ws + 41943040ull);         //  8MB [B,T,KVH,128]
    u16* vtb  = (u16*)(ws + 50331648ull);         //  8MB [B,KVH,T/64,128,64]
    u16* xh   = (u16*)(ws + 58720256ull);         // 32MB x-bf16; later q2 head-major
    u16* wbuf = (u16*)(ws + 92274688ull);         //  8MB weights; later kk
    float* cs = (float*)(ws + 100663296ull);      //  0.5MB
    float* sn = cs + TT * 64;                     //  0.5MB (total 101,711,872)
    u16* q2 = xh;                                 // [B,NH,T,128] aliases xh
    u16* kk = wbuf;                               // [B,KVH,T,128] aliases wbuf
    u16* y  = qh;                                 // attn out aliases qh

    dim3 blk(256);

    // rope tables (T=2048 > train 1024 -> NTK base scaling)
    double base = 10000.0 * pow((double)TT / 1024.0, 128.0 / 126.0);
    rope_table<<<(TT * 64) / 256, blk, 0, stream>>>(cs, sn, (float)base);

    // cast activations
    cast_f2b<<<(ROWS * DD) / 1024, blk, 0, stream>>>(x, xh, ROWS * DD);

    // projections (weight cast -> gemm, shared weight buffer)
    cast_f2b<<<(DD * DD) / 1024, blk, 0, stream>>>(q_w, wbuf, DD * DD);
    gemm_bf16_nt<1><<<dim3(DD / 128, ROWS / 128), blk, 0, stream>>>(xh, wbuf, qh, ROWS, DD, DD);
    cast_f2b<<<(512 * DD) / 1024, blk, 0, stream>>>(k_w, wbuf, 512 * DD);
    gemm_bf16_nt<1><<<dim3(512 / 128, ROWS / 128), blk, 0, stream>>>(xh, wbuf, kh, ROWS, 512, DD);
    cast_f2b<<<(512 * DD) / 1024, blk, 0, stream>>>(v_w, wbuf, 512 * DD);
    gemm_bf16_nt<1><<<dim3(512 / 128, ROWS / 128), blk, 0, stream>>>(xh, wbuf, vbh, ROWS, 512, DD);

    // fused rmsnorm + rope; Q -> head-major q2 (xh region, x dead) with
    // gain*scale*log2e folded; K -> head-major kk (wbuf region, weights dead)
    const float pre_q = 0.08838834764831845f * 1.4426950408889634f;
    rmsrope_bf16<<<(ROWS * NH) / 4, blk, 0, stream>>>(qh, q2, cs, sn, q_gain, NH, 1, pre_q, 1);
    rmsrope_bf16<<<(ROWS * NKV) / 4, blk, 0, stream>>>(kh, kk, cs, sn, nullptr, NKV, 0, 1.0f, 1);

    // V -> [B,KVH,T/64,128,64] with per-32 key permutation
    transpose_v<<<dim3(TT / 64, 2, BB * NKV), blk, 0, stream>>>(vbh, vtb);

    // attention -> y (qh region; proj-Q dead after rmsrope)
    attn_mfma<<<dim3(16, NH, BB), blk, 0, stream>>>(q2, kk, vtb, y);

    // output projection (fp32 out); wbuf overwrite safe (kk dead after attn)
    cast_f2b<<<(DD * DD) / 1024, blk, 0, stream>>>(out_w, wbuf, DD * DD);
    gemm_bf16_nt<0><<<dim3(DD / 128, ROWS / 128), blk, 0, stream>>>(y, wbuf, out, ROWS, DD, DD);
}

// Round 8
// 478.092 us; speedup vs baseline: 1.9324x; 1.1490x over previous
//
#include <hip/hip_runtime.h>
#include <math.h>

#define HEAD_DIM 128
#define NH 16
#define NKV 4
#define BB 4
#define TT 2048
#define DD 2048
#define ROWS (BB*TT)   // 8192

typedef unsigned short u16;
typedef unsigned int u32;
typedef __attribute__((ext_vector_type(8))) short short8;
typedef __attribute__((ext_vector_type(4))) float f32x4;
typedef __attribute__((ext_vector_type(16))) float f32x16;
typedef __attribute__((ext_vector_type(4))) unsigned short u16x4;

__device__ __forceinline__ float bf2f(u16 u) {
    union { unsigned int i; float f; } v; v.i = ((unsigned int)u) << 16; return v.f;
}
__device__ __forceinline__ u16 f2bf(float f) {
    union { float f; unsigned int i; } v; v.f = f;
    unsigned int r = v.i + 0x7FFFu + ((v.i >> 16) & 1u);   // round-to-nearest-even
    return (u16)(r >> 16);
}
__device__ __forceinline__ f32x4 mfma16(short8 a, short8 b, f32x4 c) {
    return __builtin_amdgcn_mfma_f32_16x16x32_bf16(a, b, c, 0, 0, 0);
}
__device__ __forceinline__ f32x16 mfma32(short8 a, short8 b, f32x16 c) {
    return __builtin_amdgcn_mfma_f32_32x32x16_bf16(a, b, c, 0, 0, 0);
}
__device__ __forceinline__ f32x16 zero16() {
    f32x16 z;
    #pragma unroll
    for (int i = 0; i < 16; ++i) z[i] = 0.f;
    return z;
}
// async global->LDS, 16B per lane; lds dest wave-uniform (HW adds lane*16)
__device__ __forceinline__ void gload_lds16(const u16* g, u16* l) {
    __builtin_amdgcn_global_load_lds(
        (const __attribute__((address_space(1))) unsigned int*)(const void*)g,
        (__attribute__((address_space(3))) unsigned int*)(void*)l, 16, 0, 0);
}

// ---------------------------------------------------------------------------
// fp32 -> bf16 cast
// ---------------------------------------------------------------------------
__global__ __launch_bounds__(256)
void cast_f2b(const float* __restrict__ in, u16* __restrict__ out, int n)
{
    int i = (blockIdx.x * 256 + threadIdx.x) * 4;
    if (i >= n) return;
    float4 v = *(const float4*)(in + i);
    u16x4 o;
    o.x = f2bf(v.x); o.y = f2bf(v.y); o.z = f2bf(v.z); o.w = f2bf(v.w);
    *(u16x4*)(out + i) = o;
}

// ---------------------------------------------------------------------------
// RoPE tables
// ---------------------------------------------------------------------------
__global__ __launch_bounds__(256)
void rope_table(float* __restrict__ cs, float* __restrict__ sn, float base)
{
    int idx = blockIdx.x * 256 + threadIdx.x;
    if (idx >= TT * 64) return;
    int t = idx >> 6;
    int d = idx & 63;
    float inv = powf(base, -(float)(2 * d) / 128.0f);
    float f = (float)t * inv;
    cs[idx] = cosf(f);
    sn[idx] = sinf(f);
}

// ---------------------------------------------------------------------------
// Fused per-head RMSNorm + rotary (+gain) with pre-scale folding.
// relayout=0: out row = in row. relayout=1: out row = (b*heads+h)*T + t.
// ---------------------------------------------------------------------------
__global__ __launch_bounds__(256)
void rmsrope_bf16(const u16* __restrict__ xin, u16* __restrict__ xout,
                  const float* __restrict__ cs, const float* __restrict__ sn,
                  const float* __restrict__ gain,
                  int heads, int use_gain, float pre, int relayout)
{
    int row  = blockIdx.x * 4 + (threadIdx.x >> 6);
    int lane = threadIdx.x & 63;
    int h = row % heads;
    int t = (row / heads) % TT;
    int b = row / (heads * TT);
    size_t base = (size_t)row * HEAD_DIM;

    float x1 = bf2f(xin[base + lane]);
    float x2 = bf2f(xin[base + 64 + lane]);
    float ss = x1 * x1 + x2 * x2;
    #pragma unroll
    for (int m = 1; m < 64; m <<= 1) ss += __shfl_xor(ss, m, 64);
    float r = 1.0f / sqrtf(ss * (1.0f / 128.0f) + 1.1920929e-7f);
    x1 *= r; x2 *= r;

    float c = cs[t * 64 + lane];
    float s = sn[t * 64 + lane];
    float o1 =  x1 * c + x2 * s;
    float o2 = -x1 * s + x2 * c;
    float g = use_gain ? gain[h] * pre : pre;
    o1 *= g; o2 *= g;

    size_t orow = relayout ? ((size_t)(b * heads + h) * TT + t) : (size_t)row;
    size_t obase = orow * HEAD_DIM;
    xout[obase + lane]      = f2bf(o1);
    xout[obase + 64 + lane] = f2bf(o2);
}

// ---------------------------------------------------------------------------
// V transpose+relayout: vbh [B,T,KVH,128] -> vt [B,KVH, T/64, 128, 64] (bf16)
// kt-tiled; per-32 key permutation (bits 2<->3), proven rounds 5-7.
// ---------------------------------------------------------------------------
__global__ __launch_bounds__(256)
void transpose_v(const u16* __restrict__ vbh, u16* __restrict__ vtb)
{
    __shared__ u16 tile[64][72];
    const int tb = blockIdx.x;
    const int db = blockIdx.y;
    const int z  = blockIdx.z;        // b*NKV + kvh
    const int tid = threadIdx.x;

    {
        const int r = tid >> 2, cq = tid & 3;
        const u16* src = vbh + ((size_t)(((z >> 2) * TT + tb * 64 + r) * NKV + (z & 3))) * 128
                             + db * 64 + cq * 16;
        short8 s0 = *(const short8*)(src);
        short8 s1 = *(const short8*)(src + 8);
        #pragma unroll
        for (int e = 0; e < 8; ++e) tile[r][cq * 16 + e]     = (u16)s0[e];
        #pragma unroll
        for (int e = 0; e < 8; ++e) tile[r][cq * 16 + 8 + e] = (u16)s1[e];
    }
    __syncthreads();
    {
        const int d = tid >> 2, tq = tid & 3;
        __attribute__((aligned(16))) u16 tmp[16];
        #pragma unroll
        for (int e = 0; e < 16; ++e) {
            int esw = (e & 3) | ((e & 4) << 1) | ((e & 8) >> 1);  // swap bits 2,3
            tmp[e] = tile[tq * 16 + esw][d];
        }
        u16* dst = vtb + (((size_t)(z * (TT / 64) + tb) * 128 + (db * 64 + d)) << 6) + tq * 16;
        *(short8*)(dst)     = ((short8*)tmp)[0];
        *(short8*)(dst + 8) = ((short8*)tmp)[1];
    }
}

// ---------------------------------------------------------------------------
// bf16 MFMA GEMM (m97 structure): C[M,N] = A[M,K] @ W[N,K]^T
// ---------------------------------------------------------------------------
template<int OUT_BF16>
__global__ __launch_bounds__(256)
void gemm_bf16_nt(const u16* __restrict__ A, const u16* __restrict__ W,
                  void* __restrict__ Cout, int M, int N, int K)
{
    __shared__ u16 As[128 * 32];
    __shared__ u16 Bs[128 * 32];
    const int tid = threadIdx.x;
    const int l = tid & 63, w = tid >> 6;
    const int lq = l & 15, lg = l >> 4;
    const int bm = blockIdx.y << 7, bn = blockIdx.x << 7;
    const int wr = (w >> 1) << 6, wc = (w & 1) << 6;

    f32x4 acc[4][4];
    #pragma unroll
    for (int m = 0; m < 4; ++m)
        #pragma unroll
        for (int n = 0; n < 4; ++n)
            acc[m][n] = (f32x4){0.f, 0.f, 0.f, 0.f};

    const int srowA = w * 16 + (l >> 2);
    const int scol  = (l & 3) << 3;
    const u16* ag0 = A + (size_t)(bm + srowA) * K + scol;
    const u16* ag1 = A + (size_t)(bm + 64 + srowA) * K + scol;
    const u16* bg0 = W + (size_t)(bn + srowA) * K + scol;
    const u16* bg1 = W + (size_t)(bn + 64 + srowA) * K + scol;
    u16* asd0 = As + (w * 16) * 32;
    u16* asd1 = As + (64 + w * 16) * 32;
    u16* bsd0 = Bs + (w * 16) * 32;
    u16* bsd1 = Bs + (64 + w * 16) * 32;

    for (int kt = 0; kt < K; kt += 32) {
        __syncthreads();
        gload_lds16(ag0 + kt, asd0);
        gload_lds16(ag1 + kt, asd1);
        gload_lds16(bg0 + kt, bsd0);
        gload_lds16(bg1 + kt, bsd1);
        __syncthreads();

        short8 af[4], bf[4];
        #pragma unroll
        for (int m = 0; m < 4; ++m)
            af[m] = *(const short8*)(As + (wr + m * 16 + lq) * 32 + lg * 8);
        #pragma unroll
        for (int n = 0; n < 4; ++n)
            bf[n] = *(const short8*)(Bs + (wc + n * 16 + lq) * 32 + lg * 8);
        #pragma unroll
        for (int m = 0; m < 4; ++m)
            #pragma unroll
            for (int n = 0; n < 4; ++n)
                acc[m][n] = mfma16(af[m], bf[n], acc[m][n]);
    }

    #pragma unroll
    for (int m = 0; m < 4; ++m) {
        int grow = bm + wr + m * 16 + lg * 4;
        #pragma unroll
        for (int n = 0; n < 4; ++n) {
            int gcol = bn + wc + n * 16 + lq;
            #pragma unroll
            for (int q = 0; q < 4; ++q) {
                if (OUT_BF16)
                    ((u16*)Cout)[(size_t)(grow + q) * N + gcol] = f2bf(acc[m][n][q]);
                else
                    ((float*)Cout)[(size_t)(grow + q) * N + gcol] = acc[m][n][q];
            }
        }
    }
}

// ---------------------------------------------------------------------------
// Causal attention, fold-balanced + reg-staged + XCD-mapped.
//  - Each block: 2 q-tiles (fold f and 15-f) = uniform 34 KV-tile steps,
//    processed through ONE continuous double-buffered staging pipeline.
//  - Staging: global->regs issued EARLY (before compute), ds_write LATE
//    (after compute) -> current tile's ds_reads have no pending LDS writes,
//    so no spurious vmcnt drain; load latency hides under compute (T14).
//  - LDS XOR-swizzle on ds_write dest + same on read (proven read pattern).
//  - bid -> (xcd-major) mapping co-locates all blocks of one (b,kvh) K/V
//    stream (1MB) on one XCD for L2 residency.
//  - Swapped-operand 32x32x16 core, in-register softmax, in-lane P frags
//    (V key-permutation), defer-max, exp2 domain (proven rounds 5-7).
// ---------------------------------------------------------------------------
__global__ __launch_bounds__(256, 2)
void attn_mfma(const u16* __restrict__ qg,   // [B,NH,T,128] head-major, pre-scaled
               const u16* __restrict__ kg,   // [B,KVH,T,128]
               const u16* __restrict__ vtg,  // [B,KVH,T/64,128,64] key-permuted
               u16* __restrict__ yg)         // [B,T,NH,128]
{
    __shared__ u16 Ks[2][64 * 128];   // [key][d]  16KB each, swizzled
    __shared__ u16 Vs[2][128 * 64];   // [d][key]  16KB each, swizzled

    const int tid = threadIdx.x, wid = tid >> 6, l = tid & 63;
    const int lq = l & 31, hi = l >> 5, hi4 = hi << 2;

    // ---- XCD-aware decode: bid = slot*8 + xcd, 64 slots/XCD ----
    const int bid = blockIdx.x;
    const int xcd  = bid & 7;
    const int s    = bid >> 3;
    const int gsub = s >> 5;            // 0..1
    const int hh   = (s >> 3) & 3;      // 0..3
    const int fold = s & 7;             // 0..7
    const int g    = xcd + (gsub << 3); // b*NKV + kvh, 0..15
    const int b = g >> 2, kvh = g & 3;
    const int h = kvh * 4 + hh;

    const u16* kg_bh = kg + (((size_t)g * TT) << 7);
    const u16* vt_bh = vtg + (size_t)g * (TT / 64) * 8192;
    const u16* q_bh  = qg + (((size_t)(b * NH + h) * TT) << 7);

    const int nta = 2 * fold + 2;        // tiles for q-block `fold`
    const int NT  = 34;                  // nta + (32 - 2*fold)

    // ---- staging decomposition (per wave: K 16 rows, V 32 d-rows) ----
    const int krow = l >> 4;             // 0..3
    const int kch  = l & 15;             // 16B chunk in 256B K row
    const int vrow = l >> 3;             // 0..7
    const int vch  = l & 7;              // 16B chunk in 128B V row

    short8 sr[8];
    auto loadreg = [&](int kt) {
        const u16* ksrc = kg_bh + (((size_t)(kt * 64 + wid * 16)) << 7);
        const u16* vsrc = vt_bh + (size_t)kt * 8192 + wid * 2048;
        #pragma unroll
        for (int i = 0; i < 4; ++i) {
            sr[i]     = *(const short8*)(ksrc + (i * 4 + krow) * 128 + kch * 8);
            sr[4 + i] = *(const short8*)(vsrc + (i * 8 + vrow) * 64 + vch * 8);
        }
    };
    auto writelds = [&](int buf) {
        u16* kd = &Ks[buf][wid * 2048];
        u16* vd = &Vs[buf][wid * 2048];
        #pragma unroll
        for (int i = 0; i < 4; ++i) {
            int kr = i * 4 + krow;
            *(short8*)(kd + kr * 128 + ((kch ^ (kr & 7)) << 3)) = sr[i];
            int vr = i * 8 + vrow;
            *(short8*)(vd + vr * 64 + ((vch ^ (vr & 7)) << 3)) = sr[4 + i];
        }
    };

    // ---- prologue: stage tile 0 into buf 0 ----
    loadreg(0);
    writelds(0);
    __syncthreads();

    int cur = 0, step = 0;

    for (int seg = 0; seg < 2; ++seg) {
        const int qblk = seg ? (15 - fold) : fold;
        const int nseg = seg ? (32 - 2 * fold) : nta;
        const int qrow = qblk * 128 + wid * 32 + lq;
        const int diag = (qblk * 128 + wid * 32) >> 6;

        // Q fragments for this segment
        const u16* qptr = q_bh + ((size_t)qrow << 7) + hi * 8;
        short8 qf[8];
        #pragma unroll
        for (int q = 0; q < 8; ++q)
            qf[q] = *(const short8*)(qptr + q * 16);

        f32x16 accO[4];
        #pragma unroll
        for (int d = 0; d < 4; ++d) accO[d] = zero16();
        float m2 = -1e30f, lr = 0.f;

        for (int kt = 0; kt < nseg; ++kt) {
            ++step;
            const bool more = step < NT;
            if (more) {
                int ktn = (step < nta) ? step : step - nta;
                loadreg(ktn);            // issue early; used after compute
            }

            if (kt <= diag) {
                // ---- S^T = K·Q (16 MFMA) ----
                const u16* Kc = Ks[cur];
                f32x16 accS0 = zero16(), accS1 = zero16();
                __builtin_amdgcn_s_setprio(1);
                #pragma unroll
                for (int ss = 0; ss < 8; ++ss) {
                    int c = ((2 * ss + hi) ^ (lq & 7)) << 3;
                    short8 kf0 = *(const short8*)(Kc + (lq << 7) + c);
                    accS0 = mfma32(kf0, qf[ss], accS0);
                    short8 kf1 = *(const short8*)(Kc + ((32 + lq) << 7) + c);
                    accS1 = mfma32(kf1, qf[ss], accS1);
                }
                __builtin_amdgcn_s_setprio(0);

                // ---- scores + causal mask (diag tile only) ----
                float p[32];
                if (kt == diag) {
                    #pragma unroll
                    for (int r = 0; r < 16; ++r) {
                        int key0 = kt * 64 + (r & 3) + 8 * (r >> 2) + hi4;
                        p[r]      = (key0      > qrow) ? -INFINITY : accS0[r];
                        p[16 + r] = (key0 + 32 > qrow) ? -INFINITY : accS1[r];
                    }
                } else {
                    #pragma unroll
                    for (int r = 0; r < 16; ++r) { p[r] = accS0[r]; p[16 + r] = accS1[r]; }
                }

                // ---- row max ----
                float t16[16];
                #pragma unroll
                for (int i = 0; i < 16; ++i) t16[i] = fmaxf(p[i], p[i + 16]);
                #pragma unroll
                for (int i = 0; i < 8; ++i) t16[i] = fmaxf(t16[i], t16[i + 8]);
                #pragma unroll
                for (int i = 0; i < 4; ++i) t16[i] = fmaxf(t16[i], t16[i + 4]);
                float pm = fmaxf(fmaxf(t16[0], t16[1]), fmaxf(t16[2], t16[3]));
                pm = fmaxf(pm, __shfl_xor(pm, 32, 64));

                // ---- defer-max ----
                float mn = m2;
                if (!__all(pm - m2 <= 8.0f)) {
                    mn = fmaxf(m2, pm);
                    float al = exp2f(m2 - mn);
                    lr *= al;
                    #pragma unroll
                    for (int d = 0; d < 4; ++d) accO[d] *= al;
                    m2 = mn;
                }

                // ---- exp2 + row sum ----
                #pragma unroll
                for (int r = 0; r < 32; ++r) p[r] = exp2f(p[r] - mn);
                #pragma unroll
                for (int i = 0; i < 16; ++i) t16[i] = p[i] + p[i + 16];
                #pragma unroll
                for (int i = 0; i < 8; ++i) t16[i] += t16[i + 8];
                #pragma unroll
                for (int i = 0; i < 4; ++i) t16[i] += t16[i + 4];
                float rs = (t16[0] + t16[1]) + (t16[2] + t16[3]);
                rs += __shfl_xor(rs, 32, 64);
                lr += rs;

                // ---- P -> bf16 B-fragments, in-lane ----
                short8 pfrag[4];
                #pragma unroll
                for (int kb = 0; kb < 2; ++kb)
                    #pragma unroll
                    for (int c = 0; c < 2; ++c) {
                        union { u16 e[8]; short8 s8; } f;
                        #pragma unroll
                        for (int j = 0; j < 8; ++j)
                            f.e[j] = f2bf(p[kb * 16 + 8 * c + j]);
                        pfrag[kb * 2 + c] = f.s8;
                    }

                // ---- O^T += V^T · P^T (16 MFMA) ----
                const u16* Vc = Vs[cur];
                #pragma unroll
                for (int d = 0; d < 4; ++d) {
                    const u16* vr8 = Vc + ((d * 32 + lq) << 6);
                    short8 vf0 = *(const short8*)(vr8 + (((0 + hi) ^ (lq & 7)) << 3));
                    short8 vf1 = *(const short8*)(vr8 + (((2 + hi) ^ (lq & 7)) << 3));
                    short8 vf2 = *(const short8*)(vr8 + (((4 + hi) ^ (lq & 7)) << 3));
                    short8 vf3 = *(const short8*)(vr8 + (((6 + hi) ^ (lq & 7)) << 3));
                    __builtin_amdgcn_s_setprio(1);
                    accO[d] = mfma32(vf0, pfrag[0], accO[d]);
                    accO[d] = mfma32(vf1, pfrag[1], accO[d]);
                    accO[d] = mfma32(vf2, pfrag[2], accO[d]);
                    accO[d] = mfma32(vf3, pfrag[3], accO[d]);
                    __builtin_amdgcn_s_setprio(0);
                }
            }

            if (more) writelds(cur ^ 1);   // vmcnt wait lands here, post-compute
            __syncthreads();
            cur ^= 1;
        }

        // ---- segment epilogue: normalize and store ----
        float inv = 1.0f / lr;
        u16* yrow = yg + ((size_t)((b * TT + qrow) * NH + h) << 7);
        #pragma unroll
        for (int d = 0; d < 4; ++d)
            #pragma unroll
            for (int r = 0; r < 4; ++r) {
                u16x4 o;
                #pragma unroll
                for (int q = 0; q < 4; ++q) o[q] = f2bf(accO[d][4 * r + q] * inv);
                *(u16x4*)(yrow + d * 32 + 8 * r + hi4) = o;
            }
    }
}

// ---------------------------------------------------------------------------
extern "C" void kernel_launch(void* const* d_in, const int* in_sizes, int n_in,
                              void* d_out, int out_size, void* d_ws, size_t ws_size,
                              hipStream_t stream)
{
    const float* x      = (const float*)d_in[0];
    const float* q_w    = (const float*)d_in[1];
    const float* k_w    = (const float*)d_in[2];
    const float* v_w    = (const float*)d_in[3];
    const float* out_w  = (const float*)d_in[4];
    const float* q_gain = (const float*)d_in[5];
    float* out = (float*)d_out;

    char* ws = (char*)d_ws;
    u16* qh   = (u16*)(ws);                       // 32MB [B,T,NH,128] proj-Q; later y
    u16* kh   = (u16*)(ws + 33554432ull);         //  8MB [B,T,KVH,128]
    u16* vbh  = (u16*)(ws + 41943040ull);         //  8MB [B,T,KVH,128]
    u16* vtb  = (u16*)(ws + 50331648ull);         //  8MB [B,KVH,T/64,128,64]
    u16* xh   = (u16*)(ws + 58720256ull);         // 32MB x-bf16; later q2 head-major
    u16* wbuf = (u16*)(ws + 92274688ull);         //  8MB weights; later kk
    float* cs = (float*)(ws + 100663296ull);      //  0.5MB
    float* sn = cs + TT * 64;                     //  0.5MB (total 101,711,872)
    u16* q2 = xh;                                 // [B,NH,T,128] aliases xh
    u16* kk = wbuf;                               // [B,KVH,T,128] aliases wbuf
    u16* y  = qh;                                 // attn out aliases qh

    dim3 blk(256);

    // rope tables (T=2048 > train 1024 -> NTK base scaling)
    double base = 10000.0 * pow((double)TT / 1024.0, 128.0 / 126.0);
    rope_table<<<(TT * 64) / 256, blk, 0, stream>>>(cs, sn, (float)base);

    // cast activations
    cast_f2b<<<(ROWS * DD) / 1024, blk, 0, stream>>>(x, xh, ROWS * DD);

    // projections (weight cast -> gemm, shared weight buffer)
    cast_f2b<<<(DD * DD) / 1024, blk, 0, stream>>>(q_w, wbuf, DD * DD);
    gemm_bf16_nt<1><<<dim3(DD / 128, ROWS / 128), blk, 0, stream>>>(xh, wbuf, qh, ROWS, DD, DD);
    cast_f2b<<<(512 * DD) / 1024, blk, 0, stream>>>(k_w, wbuf, 512 * DD);
    gemm_bf16_nt<1><<<dim3(512 / 128, ROWS / 128), blk, 0, stream>>>(xh, wbuf, kh, ROWS, 512, DD);
    cast_f2b<<<(512 * DD) / 1024, blk, 0, stream>>>(v_w, wbuf, 512 * DD);
    gemm_bf16_nt<1><<<dim3(512 / 128, ROWS / 128), blk, 0, stream>>>(xh, wbuf, vbh, ROWS, 512, DD);

    // fused rmsnorm + rope; Q -> head-major q2 (xh, x dead) with
    // gain*scale*log2e folded; K -> head-major kk (wbuf, weights dead)
    const float pre_q = 0.08838834764831845f * 1.4426950408889634f;
    rmsrope_bf16<<<(ROWS * NH) / 4, blk, 0, stream>>>(qh, q2, cs, sn, q_gain, NH, 1, pre_q, 1);
    rmsrope_bf16<<<(ROWS * NKV) / 4, blk, 0, stream>>>(kh, kk, cs, sn, nullptr, NKV, 0, 1.0f, 1);

    // V -> [B,KVH,T/64,128,64] with per-32 key permutation
    transpose_v<<<dim3(TT / 64, 2, BB * NKV), blk, 0, stream>>>(vbh, vtb);

    // attention -> y (qh region; proj-Q dead after rmsrope). Grid 512 uniform.
    attn_mfma<<<dim3(512), blk, 0, stream>>>(q2, kk, vtb, y);

    // output projection (fp32 out); wbuf overwrite safe (kk dead after attn)
    cast_f2b<<<(DD * DD) / 1024, blk, 0, stream>>>(out_w, wbuf, DD * DD);
    gemm_bf16_nt<0><<<dim3(DD / 128, ROWS / 128), blk, 0, stream>>>(y, wbuf, out, ROWS, DD, DD);
}

// Round 9
// 387.212 us; speedup vs baseline: 2.3859x; 1.2347x over previous
//
#include <hip/hip_runtime.h>
#include <hip/hip_bf16.h>
#include <math.h>

#define HEAD_DIM 128
#define NH 16
#define NKV 4
#define BB 4
#define TT 2048
#define DD 2048
#define ROWS (BB*TT)   // 8192

typedef unsigned short u16;
typedef unsigned int u32;
typedef __attribute__((ext_vector_type(8))) short short8;
typedef __attribute__((ext_vector_type(4))) float f32x4;
typedef __attribute__((ext_vector_type(16))) float f32x16;
typedef __attribute__((ext_vector_type(4))) unsigned short u16x4;

__device__ __forceinline__ float bf2f(u16 u) {
    union { unsigned int i; float f; } v; v.i = ((unsigned int)u) << 16; return v.f;
}
__device__ __forceinline__ u16 f2bf(float f) {
    union { float f; unsigned int i; } v; v.f = f;
    unsigned int r = v.i + 0x7FFFu + ((v.i >> 16) & 1u);   // round-to-nearest-even
    return (u16)(r >> 16);
}
__device__ __forceinline__ f32x4 mfma16(short8 a, short8 b, f32x4 c) {
    return __builtin_amdgcn_mfma_f32_16x16x32_bf16(a, b, c, 0, 0, 0);
}
__device__ __forceinline__ f32x16 mfma32(short8 a, short8 b, f32x16 c) {
    return __builtin_amdgcn_mfma_f32_32x32x16_bf16(a, b, c, 0, 0, 0);
}
__device__ __forceinline__ f32x16 zero16() {
    f32x16 z;
    #pragma unroll
    for (int i = 0; i < 16; ++i) z[i] = 0.f;
    return z;
}
// async global->LDS, 16B per lane; lds dest wave-uniform (HW adds lane*16)
__device__ __forceinline__ void gload_lds16(const u16* g, u16* l) {
    __builtin_amdgcn_global_load_lds(
        (const __attribute__((address_space(1))) unsigned int*)(const void*)g,
        (__attribute__((address_space(3))) unsigned int*)(void*)l, 16, 0, 0);
}
// 1D bid -> (bm,bn): bijective XCD chunking + 4x4 supertiles (L2 working set
// = 4 A-panels + 4 B-panels = 4MB = one XCD L2). Requires nblk%8==0, nbx%4==0.
__device__ __forceinline__ void decode_tile(int bid, int nblk, int nbx,
                                            int& bm, int& bn) {
    const int per = nblk >> 3;
    const int wg = (bid & 7) * per + (bid >> 3);
    const int st = wg >> 4, wi = wg & 15;
    const int stw = nbx >> 2;
    const int sty = st / stw, stx = st - sty * stw;
    bm = sty * 4 + (wi >> 2);
    bn = stx * 4 + (wi & 3);
}

// ---------------------------------------------------------------------------
// fp32 -> bf16 cast
// ---------------------------------------------------------------------------
__global__ __launch_bounds__(256)
void cast_f2b(const float* __restrict__ in, u16* __restrict__ out, int n)
{
    int i = (blockIdx.x * 256 + threadIdx.x) * 4;
    if (i >= n) return;
    float4 v = *(const float4*)(in + i);
    u16x4 o;
    o.x = f2bf(v.x); o.y = f2bf(v.y); o.z = f2bf(v.z); o.w = f2bf(v.w);
    *(u16x4*)(out + i) = o;
}

// ---------------------------------------------------------------------------
// RoPE tables
// ---------------------------------------------------------------------------
__global__ __launch_bounds__(256)
void rope_table(float* __restrict__ cs, float* __restrict__ sn, float base)
{
    int idx = blockIdx.x * 256 + threadIdx.x;
    if (idx >= TT * 64) return;
    int t = idx >> 6;
    int d = idx & 63;
    float inv = powf(base, -(float)(2 * d) / 128.0f);
    float f = (float)t * inv;
    cs[idx] = cosf(f);
    sn[idx] = sinf(f);
}

// ---------------------------------------------------------------------------
// Fused per-head RMSNorm + rotary (+gain) with pre-scale folding.
// relayout=0: out row = in row. relayout=1: out row = (b*heads+h)*T + t.
// ---------------------------------------------------------------------------
__global__ __launch_bounds__(256)
void rmsrope_bf16(const u16* __restrict__ xin, u16* __restrict__ xout,
                  const float* __restrict__ cs, const float* __restrict__ sn,
                  const float* __restrict__ gain,
                  int heads, int use_gain, float pre, int relayout)
{
    int row  = blockIdx.x * 4 + (threadIdx.x >> 6);
    int lane = threadIdx.x & 63;
    int h = row % heads;
    int t = (row / heads) % TT;
    int b = row / (heads * TT);
    size_t base = (size_t)row * HEAD_DIM;

    float x1 = bf2f(xin[base + lane]);
    float x2 = bf2f(xin[base + 64 + lane]);
    float ss = x1 * x1 + x2 * x2;
    #pragma unroll
    for (int m = 1; m < 64; m <<= 1) ss += __shfl_xor(ss, m, 64);
    float r = 1.0f / sqrtf(ss * (1.0f / 128.0f) + 1.1920929e-7f);
    x1 *= r; x2 *= r;

    float c = cs[t * 64 + lane];
    float s = sn[t * 64 + lane];
    float o1 =  x1 * c + x2 * s;
    float o2 = -x1 * s + x2 * c;
    float g = use_gain ? gain[h] * pre : pre;
    o1 *= g; o2 *= g;

    size_t orow = relayout ? ((size_t)(b * heads + h) * TT + t) : (size_t)row;
    size_t obase = orow * HEAD_DIM;
    xout[obase + lane]      = f2bf(o1);
    xout[obase + 64 + lane] = f2bf(o2);
}

// ---------------------------------------------------------------------------
// V transpose+relayout: vbh [B,T,KVH,128] -> vt [B,KVH, T/64, 128, 64] (bf16)
// kt-tiled; per-32 key permutation (bits 2<->3), proven rounds 5-8.
// ---------------------------------------------------------------------------
__global__ __launch_bounds__(256)
void transpose_v(const u16* __restrict__ vbh, u16* __restrict__ vtb)
{
    __shared__ u16 tile[64][72];
    const int tb = blockIdx.x;
    const int db = blockIdx.y;
    const int z  = blockIdx.z;        // b*NKV + kvh
    const int tid = threadIdx.x;

    {
        const int r = tid >> 2, cq = tid & 3;
        const u16* src = vbh + ((size_t)(((z >> 2) * TT + tb * 64 + r) * NKV + (z & 3))) * 128
                             + db * 64 + cq * 16;
        short8 s0 = *(const short8*)(src);
        short8 s1 = *(const short8*)(src + 8);
        #pragma unroll
        for (int e = 0; e < 8; ++e) tile[r][cq * 16 + e]     = (u16)s0[e];
        #pragma unroll
        for (int e = 0; e < 8; ++e) tile[r][cq * 16 + 8 + e] = (u16)s1[e];
    }
    __syncthreads();
    {
        const int d = tid >> 2, tq = tid & 3;
        __attribute__((aligned(16))) u16 tmp[16];
        #pragma unroll
        for (int e = 0; e < 16; ++e) {
            int esw = (e & 3) | ((e & 4) << 1) | ((e & 8) >> 1);  // swap bits 2,3
            tmp[e] = tile[tq * 16 + esw][d];
        }
        u16* dst = vtb + (((size_t)(z * (TT / 64) + tb) * 128 + (db * 64 + d)) << 6) + tq * 16;
        *(short8*)(dst)     = ((short8*)tmp)[0];
        *(short8*)(dst + 8) = ((short8*)tmp)[1];
    }
}

// ---------------------------------------------------------------------------
// Fused QKV GEMM: [8192,2048] @ [3072,2048]^T -> Q[8192,2048] K[8192,512]
// V[8192,512]. 128x128 tile, BK=32, global_load_lds, supertile+XCD decode.
// ---------------------------------------------------------------------------
__global__ __launch_bounds__(256)
void gemm_qkv(const u16* __restrict__ A, const u16* __restrict__ W,
              u16* __restrict__ Cq, u16* __restrict__ Ck, u16* __restrict__ Cv)
{
    __shared__ u16 As[128 * 32];
    __shared__ u16 Bs[128 * 32];
    const int tid = threadIdx.x;
    const int l = tid & 63, w = tid >> 6;
    const int lq = l & 15, lg = l >> 4;

    int bmi, bni;
    decode_tile(blockIdx.x, 24 * 64, 24, bmi, bni);
    const int bm = bmi << 7, bn = bni << 7;
    const int K = DD;

    f32x4 acc[4][4];
    #pragma unroll
    for (int m = 0; m < 4; ++m)
        #pragma unroll
        for (int n = 0; n < 4; ++n)
            acc[m][n] = (f32x4){0.f, 0.f, 0.f, 0.f};
    const int wr = (w >> 1) << 6, wc = (w & 1) << 6;

    const int srowA = w * 16 + (l >> 2);
    const int scol  = (l & 3) << 3;
    const u16* ag0 = A + (size_t)(bm + srowA) * K + scol;
    const u16* ag1 = A + (size_t)(bm + 64 + srowA) * K + scol;
    const u16* bg0 = W + (size_t)(bn + srowA) * K + scol;
    const u16* bg1 = W + (size_t)(bn + 64 + srowA) * K + scol;
    u16* asd0 = As + (w * 16) * 32;
    u16* asd1 = As + (64 + w * 16) * 32;
    u16* bsd0 = Bs + (w * 16) * 32;
    u16* bsd1 = Bs + (64 + w * 16) * 32;

    for (int kt = 0; kt < K; kt += 32) {
        __syncthreads();
        gload_lds16(ag0 + kt, asd0);
        gload_lds16(ag1 + kt, asd1);
        gload_lds16(bg0 + kt, bsd0);
        gload_lds16(bg1 + kt, bsd1);
        __syncthreads();

        short8 af[4], bf[4];
        #pragma unroll
        for (int m = 0; m < 4; ++m)
            af[m] = *(const short8*)(As + (wr + m * 16 + lq) * 32 + lg * 8);
        #pragma unroll
        for (int n = 0; n < 4; ++n)
            bf[n] = *(const short8*)(Bs + (wc + n * 16 + lq) * 32 + lg * 8);
        #pragma unroll
        for (int m = 0; m < 4; ++m)
            #pragma unroll
            for (int n = 0; n < 4; ++n)
                acc[m][n] = mfma16(af[m], bf[n], acc[m][n]);
    }

    // route output: bn<16 -> Q(2048), <20 -> K(512), else V(512)
    u16* C; int Nn, colbase;
    if (bni < 16)      { C = Cq; Nn = 2048; colbase = bn; }
    else if (bni < 20) { C = Ck; Nn = 512;  colbase = bn - 2048; }
    else               { C = Cv; Nn = 512;  colbase = bn - 2560; }

    #pragma unroll
    for (int m = 0; m < 4; ++m) {
        int grow = bm + wr + m * 16 + lg * 4;
        #pragma unroll
        for (int n = 0; n < 4; ++n) {
            int gcol = colbase + wc + n * 16 + lq;
            #pragma unroll
            for (int q = 0; q < 4; ++q)
                C[(size_t)(grow + q) * Nn + gcol] = f2bf(acc[m][n][q]);
        }
    }
}

// ---------------------------------------------------------------------------
// Output GEMM: [8192,2048] @ [2048,2048]^T -> fp32 [8192,2048]
// ---------------------------------------------------------------------------
__global__ __launch_bounds__(256)
void gemm_out(const u16* __restrict__ A, const u16* __restrict__ W,
              float* __restrict__ C)
{
    __shared__ u16 As[128 * 32];
    __shared__ u16 Bs[128 * 32];
    const int tid = threadIdx.x;
    const int l = tid & 63, w = tid >> 6;
    const int lq = l & 15, lg = l >> 4;

    int bmi, bni;
    decode_tile(blockIdx.x, 16 * 64, 16, bmi, bni);
    const int bm = bmi << 7, bn = bni << 7;
    const int K = DD, N = DD;

    f32x4 acc[4][4];
    #pragma unroll
    for (int m = 0; m < 4; ++m)
        #pragma unroll
        for (int n = 0; n < 4; ++n)
            acc[m][n] = (f32x4){0.f, 0.f, 0.f, 0.f};
    const int wr = (w >> 1) << 6, wc = (w & 1) << 6;

    const int srowA = w * 16 + (l >> 2);
    const int scol  = (l & 3) << 3;
    const u16* ag0 = A + (size_t)(bm + srowA) * K + scol;
    const u16* ag1 = A + (size_t)(bm + 64 + srowA) * K + scol;
    const u16* bg0 = W + (size_t)(bn + srowA) * K + scol;
    const u16* bg1 = W + (size_t)(bn + 64 + srowA) * K + scol;
    u16* asd0 = As + (w * 16) * 32;
    u16* asd1 = As + (64 + w * 16) * 32;
    u16* bsd0 = Bs + (w * 16) * 32;
    u16* bsd1 = Bs + (64 + w * 16) * 32;

    for (int kt = 0; kt < K; kt += 32) {
        __syncthreads();
        gload_lds16(ag0 + kt, asd0);
        gload_lds16(ag1 + kt, asd1);
        gload_lds16(bg0 + kt, bsd0);
        gload_lds16(bg1 + kt, bsd1);
        __syncthreads();

        short8 af[4], bf[4];
        #pragma unroll
        for (int m = 0; m < 4; ++m)
            af[m] = *(const short8*)(As + (wr + m * 16 + lq) * 32 + lg * 8);
        #pragma unroll
        for (int n = 0; n < 4; ++n)
            bf[n] = *(const short8*)(Bs + (wc + n * 16 + lq) * 32 + lg * 8);
        #pragma unroll
        for (int m = 0; m < 4; ++m)
            #pragma unroll
            for (int n = 0; n < 4; ++n)
                acc[m][n] = mfma16(af[m], bf[n], acc[m][n]);
    }

    #pragma unroll
    for (int m = 0; m < 4; ++m) {
        int grow = bm + wr + m * 16 + lg * 4;
        #pragma unroll
        for (int n = 0; n < 4; ++n) {
            int gcol = bn + wc + n * 16 + lq;
            #pragma unroll
            for (int q = 0; q < 4; ++q)
                C[(size_t)(grow + q) * N + gcol] = acc[m][n][q];
        }
    }
}

// ---------------------------------------------------------------------------
// Causal attention, fold-balanced + reg-staged + XCD-mapped (round-8 proven),
// with P->bf16 via v_cvt_pk_bf16_f32 (compiler-generated, RTNE).
// ---------------------------------------------------------------------------
__global__ __launch_bounds__(256, 2)
void attn_mfma(const u16* __restrict__ qg,   // [B,NH,T,128] head-major, pre-scaled
               const u16* __restrict__ kg,   // [B,KVH,T,128]
               const u16* __restrict__ vtg,  // [B,KVH,T/64,128,64] key-permuted
               u16* __restrict__ yg)         // [B,T,NH,128]
{
    __shared__ u16 Ks[2][64 * 128];
    __shared__ u16 Vs[2][128 * 64];

    const int tid = threadIdx.x, wid = tid >> 6, l = tid & 63;
    const int lq = l & 31, hi = l >> 5, hi4 = hi << 2;

    const int bid = blockIdx.x;
    const int xcd  = bid & 7;
    const int s    = bid >> 3;
    const int gsub = s >> 5;
    const int hh   = (s >> 3) & 3;
    const int fold = s & 7;
    const int g    = xcd + (gsub << 3);
    const int b = g >> 2, kvh = g & 3;
    const int h = kvh * 4 + hh;

    const u16* kg_bh = kg + (((size_t)g * TT) << 7);
    const u16* vt_bh = vtg + (size_t)g * (TT / 64) * 8192;
    const u16* q_bh  = qg + (((size_t)(b * NH + h) * TT) << 7);

    const int nta = 2 * fold + 2;
    const int NT  = 34;

    const int krow = l >> 4;
    const int kch  = l & 15;
    const int vrow = l >> 3;
    const int vch  = l & 7;

    short8 sr[8];
    auto loadreg = [&](int kt) {
        const u16* ksrc = kg_bh + (((size_t)(kt * 64 + wid * 16)) << 7);
        const u16* vsrc = vt_bh + (size_t)kt * 8192 + wid * 2048;
        #pragma unroll
        for (int i = 0; i < 4; ++i) {
            sr[i]     = *(const short8*)(ksrc + (i * 4 + krow) * 128 + kch * 8);
            sr[4 + i] = *(const short8*)(vsrc + (i * 8 + vrow) * 64 + vch * 8);
        }
    };
    auto writelds = [&](int buf) {
        u16* kd = &Ks[buf][wid * 2048];
        u16* vd = &Vs[buf][wid * 2048];
        #pragma unroll
        for (int i = 0; i < 4; ++i) {
            int kr = i * 4 + krow;
            *(short8*)(kd + kr * 128 + ((kch ^ (kr & 7)) << 3)) = sr[i];
            int vr = i * 8 + vrow;
            *(short8*)(vd + vr * 64 + ((vch ^ (vr & 7)) << 3)) = sr[4 + i];
        }
    };

    loadreg(0);
    writelds(0);
    __syncthreads();

    int cur = 0, step = 0;

    for (int seg = 0; seg < 2; ++seg) {
        const int qblk = seg ? (15 - fold) : fold;
        const int nseg = seg ? (32 - 2 * fold) : nta;
        const int qrow = qblk * 128 + wid * 32 + lq;
        const int diag = (qblk * 128 + wid * 32) >> 6;

        const u16* qptr = q_bh + ((size_t)qrow << 7) + hi * 8;
        short8 qf[8];
        #pragma unroll
        for (int q = 0; q < 8; ++q)
            qf[q] = *(const short8*)(qptr + q * 16);

        f32x16 accO[4];
        #pragma unroll
        for (int d = 0; d < 4; ++d) accO[d] = zero16();
        float m2 = -1e30f, lr = 0.f;

        for (int kt = 0; kt < nseg; ++kt) {
            ++step;
            const bool more = step < NT;
            if (more) {
                int ktn = (step < nta) ? step : step - nta;
                loadreg(ktn);
            }

            if (kt <= diag) {
                // ---- S^T = K·Q (16 MFMA) ----
                const u16* Kc = Ks[cur];
                f32x16 accS0 = zero16(), accS1 = zero16();
                __builtin_amdgcn_s_setprio(1);
                #pragma unroll
                for (int ss = 0; ss < 8; ++ss) {
                    int c = ((2 * ss + hi) ^ (lq & 7)) << 3;
                    short8 kf0 = *(const short8*)(Kc + (lq << 7) + c);
                    accS0 = mfma32(kf0, qf[ss], accS0);
                    short8 kf1 = *(const short8*)(Kc + ((32 + lq) << 7) + c);
                    accS1 = mfma32(kf1, qf[ss], accS1);
                }
                __builtin_amdgcn_s_setprio(0);

                // ---- scores + causal mask (diag tile only) ----
                float p[32];
                if (kt == diag) {
                    #pragma unroll
                    for (int r = 0; r < 16; ++r) {
                        int key0 = kt * 64 + (r & 3) + 8 * (r >> 2) + hi4;
                        p[r]      = (key0      > qrow) ? -INFINITY : accS0[r];
                        p[16 + r] = (key0 + 32 > qrow) ? -INFINITY : accS1[r];
                    }
                } else {
                    #pragma unroll
                    for (int r = 0; r < 16; ++r) { p[r] = accS0[r]; p[16 + r] = accS1[r]; }
                }

                // ---- row max ----
                float t16[16];
                #pragma unroll
                for (int i = 0; i < 16; ++i) t16[i] = fmaxf(p[i], p[i + 16]);
                #pragma unroll
                for (int i = 0; i < 8; ++i) t16[i] = fmaxf(t16[i], t16[i + 8]);
                #pragma unroll
                for (int i = 0; i < 4; ++i) t16[i] = fmaxf(t16[i], t16[i + 4]);
                float pm = fmaxf(fmaxf(t16[0], t16[1]), fmaxf(t16[2], t16[3]));
                pm = fmaxf(pm, __shfl_xor(pm, 32, 64));

                // ---- defer-max ----
                float mn = m2;
                if (!__all(pm - m2 <= 8.0f)) {
                    mn = fmaxf(m2, pm);
                    float al = exp2f(m2 - mn);
                    lr *= al;
                    #pragma unroll
                    for (int d = 0; d < 4; ++d) accO[d] *= al;
                    m2 = mn;
                }

                // ---- exp2 + row sum ----
                #pragma unroll
                for (int r = 0; r < 32; ++r) p[r] = exp2f(p[r] - mn);
                #pragma unroll
                for (int i = 0; i < 16; ++i) t16[i] = p[i] + p[i + 16];
                #pragma unroll
                for (int i = 0; i < 8; ++i) t16[i] += t16[i + 8];
                #pragma unroll
                for (int i = 0; i < 4; ++i) t16[i] += t16[i + 4];
                float rs = (t16[0] + t16[1]) + (t16[2] + t16[3]);
                rs += __shfl_xor(rs, 32, 64);
                lr += rs;

                // ---- P -> bf16 B-fragments via packed cvt (RTNE) ----
                short8 pfrag[4];
                #pragma unroll
                for (int kb = 0; kb < 2; ++kb)
                    #pragma unroll
                    for (int c = 0; c < 2; ++c) {
                        union { u32 u[4]; short8 s8; } f;
                        #pragma unroll
                        for (int j = 0; j < 4; ++j) {
                            __hip_bfloat162 hb = __float22bfloat162_rn(
                                make_float2(p[kb * 16 + 8 * c + 2 * j],
                                            p[kb * 16 + 8 * c + 2 * j + 1]));
                            f.u[j] = *reinterpret_cast<u32*>(&hb);
                        }
                        pfrag[kb * 2 + c] = f.s8;
                    }

                // ---- O^T += V^T · P^T (16 MFMA) ----
                const u16* Vc = Vs[cur];
                #pragma unroll
                for (int d = 0; d < 4; ++d) {
                    const u16* vr8 = Vc + ((d * 32 + lq) << 6);
                    short8 vf0 = *(const short8*)(vr8 + (((0 + hi) ^ (lq & 7)) << 3));
                    short8 vf1 = *(const short8*)(vr8 + (((2 + hi) ^ (lq & 7)) << 3));
                    short8 vf2 = *(const short8*)(vr8 + (((4 + hi) ^ (lq & 7)) << 3));
                    short8 vf3 = *(const short8*)(vr8 + (((6 + hi) ^ (lq & 7)) << 3));
                    __builtin_amdgcn_s_setprio(1);
                    accO[d] = mfma32(vf0, pfrag[0], accO[d]);
                    accO[d] = mfma32(vf1, pfrag[1], accO[d]);
                    accO[d] = mfma32(vf2, pfrag[2], accO[d]);
                    accO[d] = mfma32(vf3, pfrag[3], accO[d]);
                    __builtin_amdgcn_s_setprio(0);
                }
            }

            if (more) writelds(cur ^ 1);
            __syncthreads();
            cur ^= 1;
        }

        float inv = 1.0f / lr;
        u16* yrow = yg + ((size_t)((b * TT + qrow) * NH + h) << 7);
        #pragma unroll
        for (int d = 0; d < 4; ++d)
            #pragma unroll
            for (int r = 0; r < 4; ++r) {
                u16x4 o;
                #pragma unroll
                for (int q = 0; q < 4; ++q) o[q] = f2bf(accO[d][4 * r + q] * inv);
                *(u16x4*)(yrow + d * 32 + 8 * r + hi4) = o;
            }
    }
}

// ---------------------------------------------------------------------------
extern "C" void kernel_launch(void* const* d_in, const int* in_sizes, int n_in,
                              void* d_out, int out_size, void* d_ws, size_t ws_size,
                              hipStream_t stream)
{
    const float* x      = (const float*)d_in[0];
    const float* q_w    = (const float*)d_in[1];
    const float* k_w    = (const float*)d_in[2];
    const float* v_w    = (const float*)d_in[3];
    const float* out_w  = (const float*)d_in[4];
    const float* q_gain = (const float*)d_in[5];
    float* out = (float*)d_out;

    char* ws = (char*)d_ws;
    u16* qh   = (u16*)(ws);                       // [0,32M)   proj-Q; later y
    u16* xh   = (u16*)(ws + 33554432ull);         // [32,64M)  x bf16; later q2
    u16* wqkv = (u16*)(ws + 67108864ull);         // [64,76.6M) QKV weights; later kk
    u16* kh   = (u16*)(ws + 79691776ull);         // [76.6..84.6M) K proj; later vtb
    u16* vbh  = (u16*)(ws + 88080384ull);         // [84.6..92.6M) V proj; later wout
    float* cs = (float*)(ws + 96468992ull);       // 0.5MB
    float* sn = cs + TT * 64;                     // 0.5MB (total 97,517,568)
    u16* q2   = xh;                               // [B,NH,T,128]
    u16* kk   = wqkv;                             // [B,KVH,T,128]
    u16* vtb  = kh;                               // [B,KVH,T/64,128,64]
    u16* wout = vbh;                              // out-proj weights bf16
    u16* y    = qh;                               // attn output

    dim3 blk(256);

    // rope tables (T=2048 > train 1024 -> NTK base scaling)
    double base = 10000.0 * pow((double)TT / 1024.0, 128.0 / 126.0);
    rope_table<<<(TT * 64) / 256, blk, 0, stream>>>(cs, sn, (float)base);

    // cast activations + fused QKV weights [q_w; k_w; v_w] (3072 x 2048)
    cast_f2b<<<(ROWS * DD) / 1024, blk, 0, stream>>>(x, xh, ROWS * DD);
    cast_f2b<<<(DD * DD) / 1024, blk, 0, stream>>>(q_w, wqkv, DD * DD);
    cast_f2b<<<(512 * DD) / 1024, blk, 0, stream>>>(k_w, wqkv + 2048 * 2048, 512 * DD);
    cast_f2b<<<(512 * DD) / 1024, blk, 0, stream>>>(v_w, wqkv + 2560 * 2048, 512 * DD);

    // fused QKV projection (supertile+XCD-swizzled)
    gemm_qkv<<<dim3(24 * 64), blk, 0, stream>>>(xh, wqkv, qh, kh, vbh);

    // fused rmsnorm + rope; Q -> head-major q2 (xh, x dead) with
    // gain*scale*log2e folded; K -> head-major kk (wqkv, weights dead)
    const float pre_q = 0.08838834764831845f * 1.4426950408889634f;
    rmsrope_bf16<<<(ROWS * NH) / 4, blk, 0, stream>>>(qh, q2, cs, sn, q_gain, NH, 1, pre_q, 1);
    rmsrope_bf16<<<(ROWS * NKV) / 4, blk, 0, stream>>>(kh, kk, cs, sn, nullptr, NKV, 0, 1.0f, 1);

    // V -> [B,KVH,T/64,128,64] (vtb aliases kh; kh dead after rmsropeK)
    transpose_v<<<dim3(TT / 64, 2, BB * NKV), blk, 0, stream>>>(vbh, vtb);

    // out-proj weights (wout aliases vbh; vbh dead after transpose_v)
    cast_f2b<<<(DD * DD) / 1024, blk, 0, stream>>>(out_w, wout, DD * DD);

    // attention -> y (qh region; proj-Q dead after rmsrope). Grid 512 uniform.
    attn_mfma<<<dim3(512), blk, 0, stream>>>(q2, kk, vtb, y);

    // output projection (fp32 out, supertile+XCD-swizzled)
    gemm_out<<<dim3(16 * 64), blk, 0, stream>>>(y, wout, out);
}

// Round 10
// 354.962 us; speedup vs baseline: 2.6027x; 1.0909x over previous
//
#include <hip/hip_runtime.h>
#include <hip/hip_bf16.h>
#include <math.h>

#define HEAD_DIM 128
#define NH 16
#define NKV 4
#define BB 4
#define TT 2048
#define DD 2048
#define ROWS (BB*TT)   // 8192

typedef unsigned short u16;
typedef unsigned int u32;
typedef __attribute__((ext_vector_type(8))) short short8;
typedef __attribute__((ext_vector_type(4))) float f32x4;
typedef __attribute__((ext_vector_type(16))) float f32x16;
typedef __attribute__((ext_vector_type(4))) unsigned short u16x4;

__device__ __forceinline__ float bf2f(u16 u) {
    union { unsigned int i; float f; } v; v.i = ((unsigned int)u) << 16; return v.f;
}
__device__ __forceinline__ u16 f2bf(float f) {
    union { float f; unsigned int i; } v; v.f = f;
    unsigned int r = v.i + 0x7FFFu + ((v.i >> 16) & 1u);   // round-to-nearest-even
    return (u16)(r >> 16);
}
__device__ __forceinline__ f32x4 mfma16(short8 a, short8 b, f32x4 c) {
    return __builtin_amdgcn_mfma_f32_16x16x32_bf16(a, b, c, 0, 0, 0);
}
__device__ __forceinline__ f32x16 mfma32(short8 a, short8 b, f32x16 c) {
    return __builtin_amdgcn_mfma_f32_32x32x16_bf16(a, b, c, 0, 0, 0);
}
__device__ __forceinline__ f32x16 zero16() {
    f32x16 z;
    #pragma unroll
    for (int i = 0; i < 16; ++i) z[i] = 0.f;
    return z;
}
// async global->LDS, 16B per lane; lds dest wave-uniform (HW adds lane*16)
__device__ __forceinline__ void gload_lds16(const u16* g, u16* l) {
    __builtin_amdgcn_global_load_lds(
        (const __attribute__((address_space(1))) unsigned int*)(const void*)g,
        (__attribute__((address_space(3))) unsigned int*)(void*)l, 16, 0, 0);
}

// ---------------------------------------------------------------------------
// fp32 -> bf16 cast
// ---------------------------------------------------------------------------
__global__ __launch_bounds__(256)
void cast_f2b(const float* __restrict__ in, u16* __restrict__ out, int n)
{
    int i = (blockIdx.x * 256 + threadIdx.x) * 4;
    if (i >= n) return;
    float4 v = *(const float4*)(in + i);
    u16x4 o;
    o.x = f2bf(v.x); o.y = f2bf(v.y); o.z = f2bf(v.z); o.w = f2bf(v.w);
    *(u16x4*)(out + i) = o;
}

// ---------------------------------------------------------------------------
// RoPE tables
// ---------------------------------------------------------------------------
__global__ __launch_bounds__(256)
void rope_table(float* __restrict__ cs, float* __restrict__ sn, float base)
{
    int idx = blockIdx.x * 256 + threadIdx.x;
    if (idx >= TT * 64) return;
    int t = idx >> 6;
    int d = idx & 63;
    float inv = powf(base, -(float)(2 * d) / 128.0f);
    float f = (float)t * inv;
    cs[idx] = cosf(f);
    sn[idx] = sinf(f);
}

// ---------------------------------------------------------------------------
// Fused per-head RMSNorm + rotary (+gain) with pre-scale folding.
// relayout=0: out row = in row. relayout=1: out row = (b*heads+h)*T + t.
// ---------------------------------------------------------------------------
__global__ __launch_bounds__(256)
void rmsrope_bf16(const u16* __restrict__ xin, u16* __restrict__ xout,
                  const float* __restrict__ cs, const float* __restrict__ sn,
                  const float* __restrict__ gain,
                  int heads, int use_gain, float pre, int relayout)
{
    int row  = blockIdx.x * 4 + (threadIdx.x >> 6);
    int lane = threadIdx.x & 63;
    int h = row % heads;
    int t = (row / heads) % TT;
    int b = row / (heads * TT);
    size_t base = (size_t)row * HEAD_DIM;

    float x1 = bf2f(xin[base + lane]);
    float x2 = bf2f(xin[base + 64 + lane]);
    float ss = x1 * x1 + x2 * x2;
    #pragma unroll
    for (int m = 1; m < 64; m <<= 1) ss += __shfl_xor(ss, m, 64);
    float r = 1.0f / sqrtf(ss * (1.0f / 128.0f) + 1.1920929e-7f);
    x1 *= r; x2 *= r;

    float c = cs[t * 64 + lane];
    float s = sn[t * 64 + lane];
    float o1 =  x1 * c + x2 * s;
    float o2 = -x1 * s + x2 * c;
    float g = use_gain ? gain[h] * pre : pre;
    o1 *= g; o2 *= g;

    size_t orow = relayout ? ((size_t)(b * heads + h) * TT + t) : (size_t)row;
    size_t obase = orow * HEAD_DIM;
    xout[obase + lane]      = f2bf(o1);
    xout[obase + 64 + lane] = f2bf(o2);
}

// ---------------------------------------------------------------------------
// V transpose+relayout: vbh [B,T,KVH,128] -> vt [B,KVH, T/64, 128, 64] (bf16)
// kt-tiled; per-32 key permutation (bits 2<->3), proven rounds 5-9.
// ---------------------------------------------------------------------------
__global__ __launch_bounds__(256)
void transpose_v(const u16* __restrict__ vbh, u16* __restrict__ vtb)
{
    __shared__ u16 tile[64][72];
    const int tb = blockIdx.x;
    const int db = blockIdx.y;
    const int z  = blockIdx.z;        // b*NKV + kvh
    const int tid = threadIdx.x;

    {
        const int r = tid >> 2, cq = tid & 3;
        const u16* src = vbh + ((size_t)(((z >> 2) * TT + tb * 64 + r) * NKV + (z & 3))) * 128
                             + db * 64 + cq * 16;
        short8 s0 = *(const short8*)(src);
        short8 s1 = *(const short8*)(src + 8);
        #pragma unroll
        for (int e = 0; e < 8; ++e) tile[r][cq * 16 + e]     = (u16)s0[e];
        #pragma unroll
        for (int e = 0; e < 8; ++e) tile[r][cq * 16 + 8 + e] = (u16)s1[e];
    }
    __syncthreads();
    {
        const int d = tid >> 2, tq = tid & 3;
        __attribute__((aligned(16))) u16 tmp[16];
        #pragma unroll
        for (int e = 0; e < 16; ++e) {
            int esw = (e & 3) | ((e & 4) << 1) | ((e & 8) >> 1);  // swap bits 2,3
            tmp[e] = tile[tq * 16 + esw][d];
        }
        u16* dst = vtb + (((size_t)(z * (TT / 64) + tb) * 128 + (db * 64 + d)) << 6) + tq * 16;
        *(short8*)(dst)     = ((short8*)tmp)[0];
        *(short8*)(dst + 8) = ((short8*)tmp)[1];
    }
}

// ---------------------------------------------------------------------------
// 256-tile GEMM, counted-vmcnt pipeline (raw s_barrier, NO __syncthreads).
// C[M=8192, N] = A[M,2048] @ W[N,2048]^T, bf16 in, 512 threads, 8 waves.
// BN=256: waves 2Mx4N (128x64 each), LDS 128KB. BN=128: 4Mx2N, LDS 96KB.
// Staging: global_load_lds w/ PRE-SWIZZLED source chunk ((l&7)^(l>>3));
// reads XOR chunk^(row&7) -> conflict-free (rule #21 both-sides pattern).
// Schedule per K-tile t: compute(buf) -> sched_barrier+barrier ->
//   stage(t+2 -> buf) -> vmcnt(TIS) [tile t+1 landed] -> barrier.
// OUTMODE: 0 = bf16 C0 (N=2048); 1 = split K/V bf16 (N=1024, 512 each);
//          2 = fp32 C0 (N=2048).
// ---------------------------------------------------------------------------
template<int BN, int OUTMODE>
__global__ __launch_bounds__(512, 2)
void gemm256(const u16* __restrict__ A, const u16* __restrict__ W,
             void* __restrict__ C0, void* __restrict__ C1)
{
    constexpr int WN    = (BN == 256) ? 4 : 2;     // waves along N
    constexpr int MR    = (BN == 256) ? 8 : 4;     // M fragments per wave
    constexpr int WROW  = (BN == 256) ? 128 : 64;  // wave M extent
    constexpr int NT    = DD / 64;                 // 32 K-tiles
    constexpr int BROWS = BN / 8;                  // B rows staged per wave
    constexpr int NBI   = BROWS / 8;               // B issues per wave

    __shared__ u16 AsL[2 * 256 * 64];
    __shared__ u16 BsL[2 * BN * 64];

    const int tid = threadIdx.x;
    const int w = tid >> 6, l = tid & 63;
    const int lq = l & 15, lg = l >> 4;
    const int wmi = (WN == 4) ? (w >> 2) : (w >> 1);
    const int wni = w & (WN - 1);

    // bijective XCD chunking + 2x2 supertiles (32 M-tiles x 8 N-tiles, 256 wg)
    int bmi, bni;
    {
        const int bid = blockIdx.x;
        const int wg = (bid & 7) * 32 + (bid >> 3);
        const int st = wg >> 2, wi = wg & 3;
        const int sty = st >> 2, stx = st & 3;
        bmi = sty * 2 + (wi >> 1);
        bni = stx * 2 + (wi & 1);
    }
    const int bm = bmi * 256, bn = bni * BN;

    // per-lane staging source (pre-swizzled chunk)
    const int r8 = l >> 3;
    const int chs = (l & 7) ^ r8;
    const u16* Ag = A + (size_t)(bm + r8) * DD + chs * 8;
    const u16* Wg = W + (size_t)(bn + r8) * DD + chs * 8;

    f32x4 acc[MR][4];
    #pragma unroll
    for (int m = 0; m < MR; ++m)
        #pragma unroll
        for (int n = 0; n < 4; ++n) acc[m][n] = (f32x4){0.f, 0.f, 0.f, 0.f};

    auto stage = [&](int buf, int t) {
        const size_t ko = (size_t)t * 64;
        u16* Ad = AsL + buf * (256 * 64);
        u16* Bd = BsL + buf * (BN * 64);
        #pragma unroll
        for (int j = 0; j < 4; ++j) {
            int rb = w * 32 + j * 8;
            gload_lds16(Ag + (size_t)rb * DD + ko, Ad + rb * 64);
        }
        #pragma unroll
        for (int j = 0; j < NBI; ++j) {
            int rb = w * BROWS + j * 8;
            gload_lds16(Wg + (size_t)rb * DD + ko, Bd + rb * 64);
        }
    };

    stage(0, 0);
    stage(1, 1);
    if constexpr (BN == 256) asm volatile("s_waitcnt vmcnt(8)" ::: "memory");
    else                     asm volatile("s_waitcnt vmcnt(6)" ::: "memory");
    __builtin_amdgcn_s_barrier();
    __builtin_amdgcn_sched_barrier(0);

    const int swz = lq & 7;
    for (int t = 0; t < NT; ++t) {
        const int buf = t & 1;
        const u16* Ab = AsL + buf * (256 * 64);
        const u16* Bb = BsL + buf * (BN * 64);
        #pragma unroll
        for (int ks = 0; ks < 2; ++ks) {
            short8 af[MR], bf[4];
            #pragma unroll
            for (int m = 0; m < MR; ++m) {
                int arow = wmi * WROW + m * 16 + lq;
                af[m] = *(const short8*)(Ab + arow * 64 + (((ks * 4 + lg) ^ swz) << 3));
            }
            #pragma unroll
            for (int n = 0; n < 4; ++n) {
                int brow = wni * 64 + n * 16 + lq;
                bf[n] = *(const short8*)(Bb + brow * 64 + (((ks * 4 + lg) ^ swz) << 3));
            }
            __builtin_amdgcn_s_setprio(1);
            #pragma unroll
            for (int m = 0; m < MR; ++m)
                #pragma unroll
                for (int n = 0; n < 4; ++n)
                    acc[m][n] = mfma16(af[m], bf[n], acc[m][n]);
            __builtin_amdgcn_s_setprio(0);
        }

        if (t + 1 < NT) {
            __builtin_amdgcn_sched_barrier(0);
            __builtin_amdgcn_s_barrier();            // all waves done reading buf
            if (t + 2 < NT) {
                stage(buf, t + 2);
                if constexpr (BN == 256) asm volatile("s_waitcnt vmcnt(8)" ::: "memory");
                else                     asm volatile("s_waitcnt vmcnt(6)" ::: "memory");
            } else {
                asm volatile("s_waitcnt vmcnt(0)" ::: "memory");
            }
            __builtin_amdgcn_s_barrier();            // tile t+1 visible
            __builtin_amdgcn_sched_barrier(0);
        }
    }

    // epilogue: C/D layout col=lane&15, row=(lane>>4)*4+reg (proven)
    #pragma unroll
    for (int m = 0; m < MR; ++m) {
        int grow = bm + wmi * WROW + m * 16 + lg * 4;
        #pragma unroll
        for (int n = 0; n < 4; ++n) {
            int col = wni * 64 + n * 16 + lq;
            #pragma unroll
            for (int q = 0; q < 4; ++q) {
                float v = acc[m][n][q];
                if constexpr (OUTMODE == 0) {
                    ((u16*)C0)[(size_t)(grow + q) * 2048 + bn + col] = f2bf(v);
                } else if constexpr (OUTMODE == 2) {
                    ((float*)C0)[(size_t)(grow + q) * 2048 + bn + col] = v;
                } else {
                    int cg = bn + col;               // 0..1023 = [K | V]
                    if (cg < 512)
                        ((u16*)C0)[(size_t)(grow + q) * 512 + cg] = f2bf(v);
                    else
                        ((u16*)C1)[(size_t)(grow + q) * 512 + (cg - 512)] = f2bf(v);
                }
            }
        }
    }
}

// ---------------------------------------------------------------------------
// Causal attention, fold-balanced + reg-staged + XCD-mapped (round-8/9 proven)
// ---------------------------------------------------------------------------
__global__ __launch_bounds__(256, 2)
void attn_mfma(const u16* __restrict__ qg,   // [B,NH,T,128] head-major, pre-scaled
               const u16* __restrict__ kg,   // [B,KVH,T,128]
               const u16* __restrict__ vtg,  // [B,KVH,T/64,128,64] key-permuted
               u16* __restrict__ yg)         // [B,T,NH,128]
{
    __shared__ u16 Ks[2][64 * 128];
    __shared__ u16 Vs[2][128 * 64];

    const int tid = threadIdx.x, wid = tid >> 6, l = tid & 63;
    const int lq = l & 31, hi = l >> 5, hi4 = hi << 2;

    const int bid = blockIdx.x;
    const int xcd  = bid & 7;
    const int s    = bid >> 3;
    const int gsub = s >> 5;
    const int hh   = (s >> 3) & 3;
    const int fold = s & 7;
    const int g    = xcd + (gsub << 3);
    const int b = g >> 2, kvh = g & 3;
    const int h = kvh * 4 + hh;

    const u16* kg_bh = kg + (((size_t)g * TT) << 7);
    const u16* vt_bh = vtg + (size_t)g * (TT / 64) * 8192;
    const u16* q_bh  = qg + (((size_t)(b * NH + h) * TT) << 7);

    const int nta = 2 * fold + 2;
    const int NT  = 34;

    const int krow = l >> 4;
    const int kch  = l & 15;
    const int vrow = l >> 3;
    const int vch  = l & 7;

    short8 sr[8];
    auto loadreg = [&](int kt) {
        const u16* ksrc = kg_bh + (((size_t)(kt * 64 + wid * 16)) << 7);
        const u16* vsrc = vt_bh + (size_t)kt * 8192 + wid * 2048;
        #pragma unroll
        for (int i = 0; i < 4; ++i) {
            sr[i]     = *(const short8*)(ksrc + (i * 4 + krow) * 128 + kch * 8);
            sr[4 + i] = *(const short8*)(vsrc + (i * 8 + vrow) * 64 + vch * 8);
        }
    };
    auto writelds = [&](int buf) {
        u16* kd = &Ks[buf][wid * 2048];
        u16* vd = &Vs[buf][wid * 2048];
        #pragma unroll
        for (int i = 0; i < 4; ++i) {
            int kr = i * 4 + krow;
            *(short8*)(kd + kr * 128 + ((kch ^ (kr & 7)) << 3)) = sr[i];
            int vr = i * 8 + vrow;
            *(short8*)(vd + vr * 64 + ((vch ^ (vr & 7)) << 3)) = sr[4 + i];
        }
    };

    loadreg(0);
    writelds(0);
    __syncthreads();

    int cur = 0, step = 0;

    for (int seg = 0; seg < 2; ++seg) {
        const int qblk = seg ? (15 - fold) : fold;
        const int nseg = seg ? (32 - 2 * fold) : nta;
        const int qrow = qblk * 128 + wid * 32 + lq;
        const int diag = (qblk * 128 + wid * 32) >> 6;

        const u16* qptr = q_bh + ((size_t)qrow << 7) + hi * 8;
        short8 qf[8];
        #pragma unroll
        for (int q = 0; q < 8; ++q)
            qf[q] = *(const short8*)(qptr + q * 16);

        f32x16 accO[4];
        #pragma unroll
        for (int d = 0; d < 4; ++d) accO[d] = zero16();
        float m2 = -1e30f, lr = 0.f;

        for (int kt = 0; kt < nseg; ++kt) {
            ++step;
            const bool more = step < NT;
            if (more) {
                int ktn = (step < nta) ? step : step - nta;
                loadreg(ktn);
            }

            if (kt <= diag) {
                // ---- S^T = K·Q (16 MFMA) ----
                const u16* Kc = Ks[cur];
                f32x16 accS0 = zero16(), accS1 = zero16();
                __builtin_amdgcn_s_setprio(1);
                #pragma unroll
                for (int ss = 0; ss < 8; ++ss) {
                    int c = ((2 * ss + hi) ^ (lq & 7)) << 3;
                    short8 kf0 = *(const short8*)(Kc + (lq << 7) + c);
                    accS0 = mfma32(kf0, qf[ss], accS0);
                    short8 kf1 = *(const short8*)(Kc + ((32 + lq) << 7) + c);
                    accS1 = mfma32(kf1, qf[ss], accS1);
                }
                __builtin_amdgcn_s_setprio(0);

                // ---- scores + causal mask (diag tile only) ----
                float p[32];
                if (kt == diag) {
                    #pragma unroll
                    for (int r = 0; r < 16; ++r) {
                        int key0 = kt * 64 + (r & 3) + 8 * (r >> 2) + hi4;
                        p[r]      = (key0      > qrow) ? -INFINITY : accS0[r];
                        p[16 + r] = (key0 + 32 > qrow) ? -INFINITY : accS1[r];
                    }
                } else {
                    #pragma unroll
                    for (int r = 0; r < 16; ++r) { p[r] = accS0[r]; p[16 + r] = accS1[r]; }
                }

                // ---- row max ----
                float t16[16];
                #pragma unroll
                for (int i = 0; i < 16; ++i) t16[i] = fmaxf(p[i], p[i + 16]);
                #pragma unroll
                for (int i = 0; i < 8; ++i) t16[i] = fmaxf(t16[i], t16[i + 8]);
                #pragma unroll
                for (int i = 0; i < 4; ++i) t16[i] = fmaxf(t16[i], t16[i + 4]);
                float pm = fmaxf(fmaxf(t16[0], t16[1]), fmaxf(t16[2], t16[3]));
                pm = fmaxf(pm, __shfl_xor(pm, 32, 64));

                // ---- defer-max ----
                float mn = m2;
                if (!__all(pm - m2 <= 8.0f)) {
                    mn = fmaxf(m2, pm);
                    float al = exp2f(m2 - mn);
                    lr *= al;
                    #pragma unroll
                    for (int d = 0; d < 4; ++d) accO[d] *= al;
                    m2 = mn;
                }

                // ---- exp2 + row sum ----
                #pragma unroll
                for (int r = 0; r < 32; ++r) p[r] = exp2f(p[r] - mn);
                #pragma unroll
                for (int i = 0; i < 16; ++i) t16[i] = p[i] + p[i + 16];
                #pragma unroll
                for (int i = 0; i < 8; ++i) t16[i] += t16[i + 8];
                #pragma unroll
                for (int i = 0; i < 4; ++i) t16[i] += t16[i + 4];
                float rs = (t16[0] + t16[1]) + (t16[2] + t16[3]);
                rs += __shfl_xor(rs, 32, 64);
                lr += rs;

                // ---- P -> bf16 B-fragments via packed cvt (RTNE) ----
                short8 pfrag[4];
                #pragma unroll
                for (int kb = 0; kb < 2; ++kb)
                    #pragma unroll
                    for (int c = 0; c < 2; ++c) {
                        union { u32 u[4]; short8 s8; } f;
                        #pragma unroll
                        for (int j = 0; j < 4; ++j) {
                            __hip_bfloat162 hb = __float22bfloat162_rn(
                                make_float2(p[kb * 16 + 8 * c + 2 * j],
                                            p[kb * 16 + 8 * c + 2 * j + 1]));
                            f.u[j] = *reinterpret_cast<u32*>(&hb);
                        }
                        pfrag[kb * 2 + c] = f.s8;
                    }

                // ---- O^T += V^T · P^T (16 MFMA) ----
                const u16* Vc = Vs[cur];
                #pragma unroll
                for (int d = 0; d < 4; ++d) {
                    const u16* vr8 = Vc + ((d * 32 + lq) << 6);
                    short8 vf0 = *(const short8*)(vr8 + (((0 + hi) ^ (lq & 7)) << 3));
                    short8 vf1 = *(const short8*)(vr8 + (((2 + hi) ^ (lq & 7)) << 3));
                    short8 vf2 = *(const short8*)(vr8 + (((4 + hi) ^ (lq & 7)) << 3));
                    short8 vf3 = *(const short8*)(vr8 + (((6 + hi) ^ (lq & 7)) << 3));
                    __builtin_amdgcn_s_setprio(1);
                    accO[d] = mfma32(vf0, pfrag[0], accO[d]);
                    accO[d] = mfma32(vf1, pfrag[1], accO[d]);
                    accO[d] = mfma32(vf2, pfrag[2], accO[d]);
                    accO[d] = mfma32(vf3, pfrag[3], accO[d]);
                    __builtin_amdgcn_s_setprio(0);
                }
            }

            if (more) writelds(cur ^ 1);
            __syncthreads();
            cur ^= 1;
        }

        float inv = 1.0f / lr;
        u16* yrow = yg + ((size_t)((b * TT + qrow) * NH + h) << 7);
        #pragma unroll
        for (int d = 0; d < 4; ++d)
            #pragma unroll
            for (int r = 0; r < 4; ++r) {
                u16x4 o;
                #pragma unroll
                for (int q = 0; q < 4; ++q) o[q] = f2bf(accO[d][4 * r + q] * inv);
                *(u16x4*)(yrow + d * 32 + 8 * r + hi4) = o;
            }
    }
}

// ---------------------------------------------------------------------------
extern "C" void kernel_launch(void* const* d_in, const int* in_sizes, int n_in,
                              void* d_out, int out_size, void* d_ws, size_t ws_size,
                              hipStream_t stream)
{
    const float* x      = (const float*)d_in[0];
    const float* q_w    = (const float*)d_in[1];
    const float* k_w    = (const float*)d_in[2];
    const float* v_w    = (const float*)d_in[3];
    const float* out_w  = (const float*)d_in[4];
    const float* q_gain = (const float*)d_in[5];
    float* out = (float*)d_out;

    char* ws = (char*)d_ws;
    u16* qh   = (u16*)(ws);                       // [0,32M)   proj-Q; later y
    u16* xh   = (u16*)(ws + 33554432ull);         // [32,64M)  x bf16; later q2
    u16* wqkv = (u16*)(ws + 67108864ull);         // [64,76.6M) wq+wkv; later kk
    u16* kh   = (u16*)(ws + 79691776ull);         // [76.6..84.6M) K proj; later vtb
    u16* vbh  = (u16*)(ws + 88080384ull);         // [84.6..92.6M) V proj; later wout
    float* cs = (float*)(ws + 96468992ull);       // 0.5MB
    float* sn = cs + TT * 64;                     // 0.5MB (total 97,517,568)
    u16* wq   = wqkv;                             // 8MB  [2048,2048]
    u16* wkv  = wqkv + 4194304;                   // 4MB  [1024,2048] = [k_w; v_w]
    u16* q2   = xh;                               // [B,NH,T,128]
    u16* kk   = wqkv;                             // [B,KVH,T,128]
    u16* vtb  = kh;                               // [B,KVH,T/64,128,64]
    u16* wout = vbh;                              // out-proj weights bf16
    u16* y    = qh;                               // attn output

    dim3 blk(256);

    // rope tables (T=2048 > train 1024 -> NTK base scaling)
    double base = 10000.0 * pow((double)TT / 1024.0, 128.0 / 126.0);
    rope_table<<<(TT * 64) / 256, blk, 0, stream>>>(cs, sn, (float)base);

    // casts: activations + weights
    cast_f2b<<<(ROWS * DD) / 1024, blk, 0, stream>>>(x, xh, ROWS * DD);
    cast_f2b<<<(DD * DD) / 1024, blk, 0, stream>>>(q_w, wq, DD * DD);
    cast_f2b<<<(512 * DD) / 1024, blk, 0, stream>>>(k_w, wkv, 512 * DD);
    cast_f2b<<<(512 * DD) / 1024, blk, 0, stream>>>(v_w, wkv + 1048576, 512 * DD);

    // projections (counted-vmcnt 256-tile GEMMs; 256 blocks = 1/CU each)
    gemm256<256, 0><<<dim3(256), dim3(512), 0, stream>>>(xh, wq, qh, nullptr);
    gemm256<128, 1><<<dim3(256), dim3(512), 0, stream>>>(xh, wkv, kh, vbh);

    // fused rmsnorm + rope; Q -> head-major q2 (xh, x dead) with
    // gain*scale*log2e folded; K -> head-major kk (wqkv, weights dead)
    const float pre_q = 0.08838834764831845f * 1.4426950408889634f;
    rmsrope_bf16<<<(ROWS * NH) / 4, blk, 0, stream>>>(qh, q2, cs, sn, q_gain, NH, 1, pre_q, 1);
    rmsrope_bf16<<<(ROWS * NKV) / 4, blk, 0, stream>>>(kh, kk, cs, sn, nullptr, NKV, 0, 1.0f, 1);

    // V -> [B,KVH,T/64,128,64] (vtb aliases kh; kh dead after rmsropeK)
    transpose_v<<<dim3(TT / 64, 2, BB * NKV), blk, 0, stream>>>(vbh, vtb);

    // out-proj weights (wout aliases vbh; vbh dead after transpose_v)
    cast_f2b<<<(DD * DD) / 1024, blk, 0, stream>>>(out_w, wout, DD * DD);

    // attention -> y (qh region; proj-Q dead after rmsrope). Grid 512 uniform.
    attn_mfma<<<dim3(512), blk, 0, stream>>>(q2, kk, vtb, y);

    // output projection (fp32 out)
    gemm256<256, 2><<<dim3(256), dim3(512), 0, stream>>>(y, wout, out, nullptr);
}

// Round 13
// 354.758 us; speedup vs baseline: 2.6042x; 1.0006x over previous
//
#include <hip/hip_runtime.h>
#include <hip/hip_bf16.h>
#include <math.h>

#define HEAD_DIM 128
#define NH 16
#define NKV 4
#define BB 4
#define TT 2048
#define DD 2048
#define ROWS (BB*TT)   // 8192

typedef unsigned short u16;
typedef unsigned int u32;
typedef __attribute__((ext_vector_type(8))) short short8;
typedef __attribute__((ext_vector_type(4))) float f32x4;
typedef __attribute__((ext_vector_type(16))) float f32x16;
typedef __attribute__((ext_vector_type(4))) unsigned short u16x4;

__device__ __forceinline__ float bf2f(u16 u) {
    union { unsigned int i; float f; } v; v.i = ((unsigned int)u) << 16; return v.f;
}
__device__ __forceinline__ u16 f2bf(float f) {
    union { float f; unsigned int i; } v; v.f = f;
    unsigned int r = v.i + 0x7FFFu + ((v.i >> 16) & 1u);   // round-to-nearest-even
    return (u16)(r >> 16);
}
__device__ __forceinline__ f32x4 mfma16(short8 a, short8 b, f32x4 c) {
    return __builtin_amdgcn_mfma_f32_16x16x32_bf16(a, b, c, 0, 0, 0);
}
__device__ __forceinline__ f32x16 mfma32(short8 a, short8 b, f32x16 c) {
    return __builtin_amdgcn_mfma_f32_32x32x16_bf16(a, b, c, 0, 0, 0);
}
__device__ __forceinline__ f32x16 zero16() {
    f32x16 z;
    #pragma unroll
    for (int i = 0; i < 16; ++i) z[i] = 0.f;
    return z;
}
// async global->LDS, 16B per lane; lds dest wave-uniform (HW adds lane*16)
__device__ __forceinline__ void gload_lds16(const u16* g, u16* l) {
    __builtin_amdgcn_global_load_lds(
        (const __attribute__((address_space(1))) unsigned int*)(const void*)g,
        (__attribute__((address_space(3))) unsigned int*)(void*)l, 16, 0, 0);
}

// ---------------------------------------------------------------------------
// fp32 -> bf16 cast
// ---------------------------------------------------------------------------
__global__ __launch_bounds__(256)
void cast_f2b(const float* __restrict__ in, u16* __restrict__ out, int n)
{
    int i = (blockIdx.x * 256 + threadIdx.x) * 4;
    if (i >= n) return;
    float4 v = *(const float4*)(in + i);
    u16x4 o;
    o.x = f2bf(v.x); o.y = f2bf(v.y); o.z = f2bf(v.z); o.w = f2bf(v.w);
    *(u16x4*)(out + i) = o;
}

// ---------------------------------------------------------------------------
// RoPE tables
// ---------------------------------------------------------------------------
__global__ __launch_bounds__(256)
void rope_table(float* __restrict__ cs, float* __restrict__ sn, float base)
{
    int idx = blockIdx.x * 256 + threadIdx.x;
    if (idx >= TT * 64) return;
    int t = idx >> 6;
    int d = idx & 63;
    float inv = powf(base, -(float)(2 * d) / 128.0f);
    float f = (float)t * inv;
    cs[idx] = cosf(f);
    sn[idx] = sinf(f);
}

// ---------------------------------------------------------------------------
// Fused per-head RMSNorm + rotary (+gain) with pre-scale folding.
// relayout=0: out row = in row. relayout=1: out row = (b*heads+h)*T + t.
// ---------------------------------------------------------------------------
__global__ __launch_bounds__(256)
void rmsrope_bf16(const u16* __restrict__ xin, u16* __restrict__ xout,
                  const float* __restrict__ cs, const float* __restrict__ sn,
                  const float* __restrict__ gain,
                  int heads, int use_gain, float pre, int relayout)
{
    int row  = blockIdx.x * 4 + (threadIdx.x >> 6);
    int lane = threadIdx.x & 63;
    int h = row % heads;
    int t = (row / heads) % TT;
    int b = row / (heads * TT);
    size_t base = (size_t)row * HEAD_DIM;

    float x1 = bf2f(xin[base + lane]);
    float x2 = bf2f(xin[base + 64 + lane]);
    float ss = x1 * x1 + x2 * x2;
    #pragma unroll
    for (int m = 1; m < 64; m <<= 1) ss += __shfl_xor(ss, m, 64);
    float r = 1.0f / sqrtf(ss * (1.0f / 128.0f) + 1.1920929e-7f);
    x1 *= r; x2 *= r;

    float c = cs[t * 64 + lane];
    float s = sn[t * 64 + lane];
    float o1 =  x1 * c + x2 * s;
    float o2 = -x1 * s + x2 * c;
    float g = use_gain ? gain[h] * pre : pre;
    o1 *= g; o2 *= g;

    size_t orow = relayout ? ((size_t)(b * heads + h) * TT + t) : (size_t)row;
    size_t obase = orow * HEAD_DIM;
    xout[obase + lane]      = f2bf(o1);
    xout[obase + 64 + lane] = f2bf(o2);
}

// ---------------------------------------------------------------------------
// V transpose+relayout: vbh [B,T,KVH,128] -> vt [B,KVH, T/64, 128, 64] (bf16)
// kt-tiled; per-32 key permutation (bits 2<->3), proven rounds 5-10.
// ---------------------------------------------------------------------------
__global__ __launch_bounds__(256)
void transpose_v(const u16* __restrict__ vbh, u16* __restrict__ vtb)
{
    __shared__ u16 tile[64][72];
    const int tb = blockIdx.x;
    const int db = blockIdx.y;
    const int z  = blockIdx.z;        // b*NKV + kvh
    const int tid = threadIdx.x;

    {
        const int r = tid >> 2, cq = tid & 3;
        const u16* src = vbh + ((size_t)(((z >> 2) * TT + tb * 64 + r) * NKV + (z & 3))) * 128
                             + db * 64 + cq * 16;
        short8 s0 = *(const short8*)(src);
        short8 s1 = *(const short8*)(src + 8);
        #pragma unroll
        for (int e = 0; e < 8; ++e) tile[r][cq * 16 + e]     = (u16)s0[e];
        #pragma unroll
        for (int e = 0; e < 8; ++e) tile[r][cq * 16 + 8 + e] = (u16)s1[e];
    }
    __syncthreads();
    {
        const int d = tid >> 2, tq = tid & 3;
        __attribute__((aligned(16))) u16 tmp[16];
        #pragma unroll
        for (int e = 0; e < 16; ++e) {
            int esw = (e & 3) | ((e & 4) << 1) | ((e & 8) >> 1);  // swap bits 2,3
            tmp[e] = tile[tq * 16 + esw][d];
        }
        u16* dst = vtb + (((size_t)(z * (TT / 64) + tb) * 128 + (db * 64 + d)) << 6) + tq * 16;
        *(short8*)(dst)     = ((short8*)tmp)[0];
        *(short8*)(dst + 8) = ((short8*)tmp)[1];
    }
}

// ---------------------------------------------------------------------------
// 256-tile GEMM, counted-vmcnt pipeline (round-10 proven).
// ---------------------------------------------------------------------------
template<int BN, int OUTMODE>
__global__ __launch_bounds__(512, 2)
void gemm256(const u16* __restrict__ A, const u16* __restrict__ W,
             void* __restrict__ C0, void* __restrict__ C1)
{
    constexpr int WN    = (BN == 256) ? 4 : 2;
    constexpr int MR    = (BN == 256) ? 8 : 4;
    constexpr int WROW  = (BN == 256) ? 128 : 64;
    constexpr int NT    = DD / 64;
    constexpr int BROWS = BN / 8;
    constexpr int NBI   = BROWS / 8;

    __shared__ u16 AsL[2 * 256 * 64];
    __shared__ u16 BsL[2 * BN * 64];

    const int tid = threadIdx.x;
    const int w = tid >> 6, l = tid & 63;
    const int lq = l & 15, lg = l >> 4;
    const int wmi = (WN == 4) ? (w >> 2) : (w >> 1);
    const int wni = w & (WN - 1);

    int bmi, bni;
    {
        const int bid = blockIdx.x;
        const int wg = (bid & 7) * 32 + (bid >> 3);
        const int st = wg >> 2, wi = wg & 3;
        const int sty = st >> 2, stx = st & 3;
        bmi = sty * 2 + (wi >> 1);
        bni = stx * 2 + (wi & 1);
    }
    const int bm = bmi * 256, bn = bni * BN;

    const int r8 = l >> 3;
    const int chs = (l & 7) ^ r8;
    const u16* Ag = A + (size_t)(bm + r8) * DD + chs * 8;
    const u16* Wg = W + (size_t)(bn + r8) * DD + chs * 8;

    f32x4 acc[MR][4];
    #pragma unroll
    for (int m = 0; m < MR; ++m)
        #pragma unroll
        for (int n = 0; n < 4; ++n) acc[m][n] = (f32x4){0.f, 0.f, 0.f, 0.f};

    auto stage = [&](int buf, int t) {
        const size_t ko = (size_t)t * 64;
        u16* Ad = AsL + buf * (256 * 64);
        u16* Bd = BsL + buf * (BN * 64);
        #pragma unroll
        for (int j = 0; j < 4; ++j) {
            int rb = w * 32 + j * 8;
            gload_lds16(Ag + (size_t)rb * DD + ko, Ad + rb * 64);
        }
        #pragma unroll
        for (int j = 0; j < NBI; ++j) {
            int rb = w * BROWS + j * 8;
            gload_lds16(Wg + (size_t)rb * DD + ko, Bd + rb * 64);
        }
    };

    stage(0, 0);
    stage(1, 1);
    if constexpr (BN == 256) asm volatile("s_waitcnt vmcnt(8)" ::: "memory");
    else                     asm volatile("s_waitcnt vmcnt(6)" ::: "memory");
    __builtin_amdgcn_s_barrier();
    __builtin_amdgcn_sched_barrier(0);

    const int swz = lq & 7;
    for (int t = 0; t < NT; ++t) {
        const int buf = t & 1;
        const u16* Ab = AsL + buf * (256 * 64);
        const u16* Bb = BsL + buf * (BN * 64);
        #pragma unroll
        for (int ks = 0; ks < 2; ++ks) {
            short8 af[MR], bf[4];
            #pragma unroll
            for (int m = 0; m < MR; ++m) {
                int arow = wmi * WROW + m * 16 + lq;
                af[m] = *(const short8*)(Ab + arow * 64 + (((ks * 4 + lg) ^ swz) << 3));
            }
            #pragma unroll
            for (int n = 0; n < 4; ++n) {
                int brow = wni * 64 + n * 16 + lq;
                bf[n] = *(const short8*)(Bb + brow * 64 + (((ks * 4 + lg) ^ swz) << 3));
            }
            __builtin_amdgcn_s_setprio(1);
            #pragma unroll
            for (int m = 0; m < MR; ++m)
                #pragma unroll
                for (int n = 0; n < 4; ++n)
                    acc[m][n] = mfma16(af[m], bf[n], acc[m][n]);
            __builtin_amdgcn_s_setprio(0);
        }

        if (t + 1 < NT) {
            __builtin_amdgcn_sched_barrier(0);
            __builtin_amdgcn_s_barrier();
            if (t + 2 < NT) {
                stage(buf, t + 2);
                if constexpr (BN == 256) asm volatile("s_waitcnt vmcnt(8)" ::: "memory");
                else                     asm volatile("s_waitcnt vmcnt(6)" ::: "memory");
            } else {
                asm volatile("s_waitcnt vmcnt(0)" ::: "memory");
            }
            __builtin_amdgcn_s_barrier();
            __builtin_amdgcn_sched_barrier(0);
        }
    }

    #pragma unroll
    for (int m = 0; m < MR; ++m) {
        int grow = bm + wmi * WROW + m * 16 + lg * 4;
        #pragma unroll
        for (int n = 0; n < 4; ++n) {
            int col = wni * 64 + n * 16 + lq;
            #pragma unroll
            for (int q = 0; q < 4; ++q) {
                float v = acc[m][n][q];
                if constexpr (OUTMODE == 0) {
                    ((u16*)C0)[(size_t)(grow + q) * 2048 + bn + col] = f2bf(v);
                } else if constexpr (OUTMODE == 2) {
                    ((float*)C0)[(size_t)(grow + q) * 2048 + bn + col] = v;
                } else {
                    int cg = bn + col;
                    if (cg < 512)
                        ((u16*)C0)[(size_t)(grow + q) * 512 + cg] = f2bf(v);
                    else
                        ((u16*)C1)[(size_t)(grow + q) * 512 + (cg - 512)] = f2bf(v);
                }
            }
        }
    }
}

// ---------------------------------------------------------------------------
// Causal attention, fold-balanced + XCD-mapped, with counted-vmcnt
// global_load_lds staging (gemm256 schedule ported):
//   per step: compute(buf) -> sched_barrier+barrier (buf free) ->
//   stage(t+2 -> buf) -> vmcnt(8) [t+1's 8 issues landed] -> barrier.
// LDS linear dest + PRE-SWIZZLED global source chunk (chunk^(row&7)),
// reads use the identical XOR (rule #21). No ds_writes, no reg round-trip.
// Core math (swapped-operand 32x32, in-reg softmax, in-lane P frags via
// V key-permutation, defer-max, exp2 domain) proven rounds 5-10.
// ---------------------------------------------------------------------------
__global__ __launch_bounds__(256, 2)
void attn_mfma(const u16* __restrict__ qg,   // [B,NH,T,128] head-major, pre-scaled
               const u16* __restrict__ kg,   // [B,KVH,T,128]
               const u16* __restrict__ vtg,  // [B,KVH,T/64,128,64] key-permuted
               u16* __restrict__ yg)         // [B,T,NH,128]
{
    __shared__ u16 Ks[2][64 * 128];
    __shared__ u16 Vs[2][128 * 64];

    const int tid = threadIdx.x, wid = tid >> 6, l = tid & 63;
    const int lq = l & 31, hi = l >> 5, hi4 = hi << 2;

    const int bid = blockIdx.x;
    const int xcd  = bid & 7;
    const int s    = bid >> 3;
    const int gsub = s >> 5;
    const int hh   = (s >> 3) & 3;
    const int fold = s & 7;
    const int g    = xcd + (gsub << 3);
    const int b = g >> 2, kvh = g & 3;
    const int h = kvh * 4 + hh;

    const u16* kg_bh = kg + (((size_t)g * TT) << 7);
    const u16* vt_bh = vtg + (size_t)g * (TT / 64) * 8192;
    const u16* q_bh  = qg + (((size_t)(b * NH + h) * TT) << 7);

    const int nta = 2 * fold + 2;
    const int NT  = 34;

    // staging: per wave 4 K issues (16 keys x 256B) + 4 V issues (32 d x 128B)
    const int kro = l >> 4;              // row within K issue (0..3)
    const int kch = l & 15;              // 16B chunk in 256B K row
    const int vro = l >> 3;              // row within V issue (0..7)
    const int vchs = (l & 7) ^ vro;      // pre-swizzled V source chunk

    auto stage = [&](int buf, int kt) {
        #pragma unroll
        for (int i = 0; i < 4; ++i) {
            int kr = wid * 16 + i * 4 + kro;
            gload_lds16(kg_bh + (((size_t)(kt * 64 + kr)) << 7) + ((kch ^ (kr & 7)) << 3),
                        &Ks[buf][(wid * 16 + i * 4) << 7]);
            int vr = wid * 32 + i * 8 + vro;
            gload_lds16(vt_bh + (size_t)kt * 8192 + (vr << 6) + (vchs << 3),
                        &Vs[buf][(wid * 32 + i * 8) << 6]);
        }
    };

    stage(0, 0);
    stage(1, 1);
    asm volatile("s_waitcnt vmcnt(8)" ::: "memory");
    __builtin_amdgcn_s_barrier();
    __builtin_amdgcn_sched_barrier(0);

    int step = 0;

    for (int seg = 0; seg < 2; ++seg) {
        const int qblk = seg ? (15 - fold) : fold;
        const int nseg = seg ? (32 - 2 * fold) : nta;
        const int qrow = qblk * 128 + wid * 32 + lq;
        const int diag = (qblk * 128 + wid * 32) >> 6;

        const u16* qptr = q_bh + ((size_t)qrow << 7) + hi * 8;
        short8 qf[8];
        #pragma unroll
        for (int q = 0; q < 8; ++q)
            qf[q] = *(const short8*)(qptr + q * 16);

        f32x16 accO[4];
        #pragma unroll
        for (int d = 0; d < 4; ++d) accO[d] = zero16();
        float m2 = -1e30f, lr = 0.f;

        for (int kt = 0; kt < nseg; ++kt, ++step) {
            const int buf = step & 1;

            if (kt <= diag) {
                // ---- S^T = K·Q (16 MFMA) ----
                const u16* Kc = Ks[buf];
                f32x16 accS0 = zero16(), accS1 = zero16();
                __builtin_amdgcn_s_setprio(1);
                #pragma unroll
                for (int ss = 0; ss < 8; ++ss) {
                    int c = ((2 * ss + hi) ^ (lq & 7)) << 3;
                    short8 kf0 = *(const short8*)(Kc + (lq << 7) + c);
                    accS0 = mfma32(kf0, qf[ss], accS0);
                    short8 kf1 = *(const short8*)(Kc + ((32 + lq) << 7) + c);
                    accS1 = mfma32(kf1, qf[ss], accS1);
                }
                __builtin_amdgcn_s_setprio(0);

                // ---- scores + causal mask (diag tile only) ----
                float p[32];
                if (kt == diag) {
                    #pragma unroll
                    for (int r = 0; r < 16; ++r) {
                        int key0 = kt * 64 + (r & 3) + 8 * (r >> 2) + hi4;
                        p[r]      = (key0      > qrow) ? -INFINITY : accS0[r];
                        p[16 + r] = (key0 + 32 > qrow) ? -INFINITY : accS1[r];
                    }
                } else {
                    #pragma unroll
                    for (int r = 0; r < 16; ++r) { p[r] = accS0[r]; p[16 + r] = accS1[r]; }
                }

                // ---- row max ----
                float t16[16];
                #pragma unroll
                for (int i = 0; i < 16; ++i) t16[i] = fmaxf(p[i], p[i + 16]);
                #pragma unroll
                for (int i = 0; i < 8; ++i) t16[i] = fmaxf(t16[i], t16[i + 8]);
                #pragma unroll
                for (int i = 0; i < 4; ++i) t16[i] = fmaxf(t16[i], t16[i + 4]);
                float pm = fmaxf(fmaxf(t16[0], t16[1]), fmaxf(t16[2], t16[3]));
                pm = fmaxf(pm, __shfl_xor(pm, 32, 64));

                // ---- defer-max ----
                float mn = m2;
                if (!__all(pm - m2 <= 8.0f)) {
                    mn = fmaxf(m2, pm);
                    float al = exp2f(m2 - mn);
                    lr *= al;
                    #pragma unroll
                    for (int d = 0; d < 4; ++d) accO[d] *= al;
                    m2 = mn;
                }

                // ---- exp2 + row sum ----
                #pragma unroll
                for (int r = 0; r < 32; ++r) p[r] = exp2f(p[r] - mn);
                #pragma unroll
                for (int i = 0; i < 16; ++i) t16[i] = p[i] + p[i + 16];
                #pragma unroll
                for (int i = 0; i < 8; ++i) t16[i] += t16[i + 8];
                #pragma unroll
                for (int i = 0; i < 4; ++i) t16[i] += t16[i + 4];
                float rs = (t16[0] + t16[1]) + (t16[2] + t16[3]);
                rs += __shfl_xor(rs, 32, 64);
                lr += rs;

                // ---- P -> bf16 B-fragments via packed cvt (RTNE) ----
                short8 pfrag[4];
                #pragma unroll
                for (int kb = 0; kb < 2; ++kb)
                    #pragma unroll
                    for (int c = 0; c < 2; ++c) {
                        union { u32 u[4]; short8 s8; } f;
                        #pragma unroll
                        for (int j = 0; j < 4; ++j) {
                            __hip_bfloat162 hb = __float22bfloat162_rn(
                                make_float2(p[kb * 16 + 8 * c + 2 * j],
                                            p[kb * 16 + 8 * c + 2 * j + 1]));
                            f.u[j] = *reinterpret_cast<u32*>(&hb);
                        }
                        pfrag[kb * 2 + c] = f.s8;
                    }

                // ---- O^T += V^T · P^T (16 MFMA) ----
                const u16* Vc = Vs[buf];
                #pragma unroll
                for (int d = 0; d < 4; ++d) {
                    const u16* vr8 = Vc + ((d * 32 + lq) << 6);
                    short8 vf0 = *(const short8*)(vr8 + (((0 + hi) ^ (lq & 7)) << 3));
                    short8 vf1 = *(const short8*)(vr8 + (((2 + hi) ^ (lq & 7)) << 3));
                    short8 vf2 = *(const short8*)(vr8 + (((4 + hi) ^ (lq & 7)) << 3));
                    short8 vf3 = *(const short8*)(vr8 + (((6 + hi) ^ (lq & 7)) << 3));
                    __builtin_amdgcn_s_setprio(1);
                    accO[d] = mfma32(vf0, pfrag[0], accO[d]);
                    accO[d] = mfma32(vf1, pfrag[1], accO[d]);
                    accO[d] = mfma32(vf2, pfrag[2], accO[d]);
                    accO[d] = mfma32(vf3, pfrag[3], accO[d]);
                    __builtin_amdgcn_s_setprio(0);
                }
            }

            // ---- pipeline advance (all waves, uniform) ----
            if (step + 1 < NT) {
                __builtin_amdgcn_sched_barrier(0);
                __builtin_amdgcn_s_barrier();        // all waves done reading buf
                if (step + 2 < NT) {
                    int tn = step + 2;
                    stage(buf, (tn < nta) ? tn : tn - nta);
                    asm volatile("s_waitcnt vmcnt(8)" ::: "memory");
                } else {
                    asm volatile("s_waitcnt vmcnt(0)" ::: "memory");
                }
                __builtin_amdgcn_s_barrier();        // tile step+1 visible
                __builtin_amdgcn_sched_barrier(0);
            }
        }

        // ---- segment epilogue: normalize (lr lane-uniform) and store ----
        float inv = 1.0f / lr;
        u16* yrow = yg + ((size_t)((b * TT + qrow) * NH + h) << 7);
        #pragma unroll
        for (int d = 0; d < 4; ++d)
            #pragma unroll
            for (int r = 0; r < 4; ++r) {
                u16x4 o;
                #pragma unroll
                for (int q = 0; q < 4; ++q) o[q] = f2bf(accO[d][4 * r + q] * inv);
                *(u16x4*)(yrow + d * 32 + 8 * r + hi4) = o;
            }
    }
}

// ---------------------------------------------------------------------------
extern "C" void kernel_launch(void* const* d_in, const int* in_sizes, int n_in,
                              void* d_out, int out_size, void* d_ws, size_t ws_size,
                              hipStream_t stream)
{
    const float* x      = (const float*)d_in[0];
    const float* q_w    = (const float*)d_in[1];
    const float* k_w    = (const float*)d_in[2];
    const float* v_w    = (const float*)d_in[3];
    const float* out_w  = (const float*)d_in[4];
    const float* q_gain = (const float*)d_in[5];
    float* out = (float*)d_out;

    char* ws = (char*)d_ws;
    u16* qh   = (u16*)(ws);                       // [0,32M)   proj-Q; later y
    u16* xh   = (u16*)(ws + 33554432ull);         // [32,64M)  x bf16; later q2
    u16* wqkv = (u16*)(ws + 67108864ull);         // [64,76.6M) wq+wkv; later kk
    u16* kh   = (u16*)(ws + 79691776ull);         // [76.6..84.6M) K proj; later vtb
    u16* vbh  = (u16*)(ws + 88080384ull);         // [84.6..92.6M) V proj; later wout
    float* cs = (float*)(ws + 96468992ull);       // 0.5MB
    float* sn = cs + TT * 64;                     // 0.5MB (total 97,517,568)
    u16* wq   = wqkv;                             // 8MB  [2048,2048]
    u16* wkv  = wqkv + 4194304;                   // 4MB  [1024,2048] = [k_w; v_w]
    u16* q2   = xh;                               // [B,NH,T,128]
    u16* kk   = wqkv;                             // [B,KVH,T,128]
    u16* vtb  = kh;                               // [B,KVH,T/64,128,64]
    u16* wout = vbh;                              // out-proj weights bf16
    u16* y    = qh;                               // attn output

    dim3 blk(256);

    // rope tables (T=2048 > train 1024 -> NTK base scaling)
    double base = 10000.0 * pow((double)TT / 1024.0, 128.0 / 126.0);
    rope_table<<<(TT * 64) / 256, blk, 0, stream>>>(cs, sn, (float)base);

    // casts: activations + weights
    cast_f2b<<<(ROWS * DD) / 1024, blk, 0, stream>>>(x, xh, ROWS * DD);
    cast_f2b<<<(DD * DD) / 1024, blk, 0, stream>>>(q_w, wq, DD * DD);
    cast_f2b<<<(512 * DD) / 1024, blk, 0, stream>>>(k_w, wkv, 512 * DD);
    cast_f2b<<<(512 * DD) / 1024, blk, 0, stream>>>(v_w, wkv + 1048576, 512 * DD);

    // projections (counted-vmcnt 256-tile GEMMs; 256 blocks = 1/CU each)
    gemm256<256, 0><<<dim3(256), dim3(512), 0, stream>>>(xh, wq, qh, nullptr);
    gemm256<128, 1><<<dim3(256), dim3(512), 0, stream>>>(xh, wkv, kh, vbh);

    // fused rmsnorm + rope; Q -> head-major q2 (xh, x dead) with
    // gain*scale*log2e folded; K -> head-major kk (wqkv, weights dead)
    const float pre_q = 0.08838834764831845f * 1.4426950408889634f;
    rmsrope_bf16<<<(ROWS * NH) / 4, blk, 0, stream>>>(qh, q2, cs, sn, q_gain, NH, 1, pre_q, 1);
    rmsrope_bf16<<<(ROWS * NKV) / 4, blk, 0, stream>>>(kh, kk, cs, sn, nullptr, NKV, 0, 1.0f, 1);

    // V -> [B,KVH,T/64,128,64] (vtb aliases kh; kh dead after rmsropeK)
    transpose_v<<<dim3(TT / 64, 2, BB * NKV), blk, 0, stream>>>(vbh, vtb);

    // out-proj weights (wout aliases vbh; vbh dead after transpose_v)
    cast_f2b<<<(DD * DD) / 1024, blk, 0, stream>>>(out_w, wout, DD * DD);

    // attention -> y (qh region; proj-Q dead after rmsrope). Grid 512 uniform.
    attn_mfma<<<dim3(512), blk, 0, stream>>>(q2, kk, vtb, y);

    // output projection (fp32 out)
    gemm256<256, 2><<<dim3(256), dim3(512), 0, stream>>>(y, wout, out, nullptr);
}